// Round 1
// baseline (1941.500 us; speedup 1.0000x reference)
//
#include <hip/hip_runtime.h>
#include <hip/hip_bf16.h>

// TransMatch: 8-layer correlation matcher, fp32 baseline (round 0).
// Workspace layout (floats):
//   Qbuf  [2][8][16][192][512]  = 25,165,824   (sel 0=query from q_feat, 1=key from g_feat)
//   xbuf  [8][512][192]         =    786,432   (rows 2j / 2j+1 = max-over-s / max-over-t)
//   hbuf  [8][512][2048]        =  8,388,608
//   bn1s  [8][2]                =         16   (mean, rstd per layer)
//   bn2m  [8][2048], bn2r [8][2048] = 32,768
//   ybuf  [8][512]              =      4,096
// total ~34.4M floats ~137.5 MB — must fit in d_ws.

#define L_ 8
#define S_ 192
#define D_ 512
#define DFF_ 2048
#define BS_ 16
#define EPS_ 1e-5f

__device__ __forceinline__ unsigned fkey(float f) {
    unsigned u = __float_as_uint(f);
    return (u & 0x80000000u) ? ~u : (u | 0x80000000u);
}
__device__ __forceinline__ float funkey(unsigned k) {
    return (k & 0x80000000u) ? __uint_as_float(k & 0x7FFFFFFFu)
                             : __uint_as_float(~k);
}

// ---------------- K1: fc0 projection (query & key) ----------------
// OUT[sel][l][b][t][e] = sum_d feat[b, l*512+d, t] * w0[l,e,d] + b0[l,e]
__global__ __launch_bounds__(256) void k_fc0(const float* __restrict__ qfeat,
                                             const float* __restrict__ gfeat,
                                             const float* __restrict__ w0,
                                             const float* __restrict__ b0,
                                             float* __restrict__ Qbuf) {
    int bid = blockIdx.x;
    int et = bid & 7;  bid >>= 3;    // e tile: 8 x 64
    int tt = bid % 3;  bid /= 3;     // t tile: 3 x 64
    int b  = bid & 15; bid >>= 4;
    int l  = bid & 7;  bid >>= 3;
    int sel = bid;                   // 0=query, 1=key
    const float* feat  = sel ? gfeat : qfeat;
    const float* Abase = feat + (size_t)b * 4096 * 192 + (size_t)l * 512 * 192;
    const float* Wbase = w0 + (size_t)l * 512 * 512;
    int t0 = tt * 64, e0 = et * 64;

    __shared__ float As[16][68];   // [d][t]
    __shared__ float Bs[16][68];   // [d][e]
    int tid = threadIdx.x;
    int tx = tid & 15, ty = tid >> 4;
    float acc[4][4] = {};

    for (int d0 = 0; d0 < 512; d0 += 16) {
        {   // A: 16 d x 64 t (t contiguous in memory)
            int dl = tid >> 6;      // 0..3
            int tl = tid & 63;
            #pragma unroll
            for (int p = 0; p < 4; p++)
                As[dl + p * 4][tl] = Abase[(size_t)(d0 + dl + p * 4) * 192 + t0 + tl];
        }
        {   // W: 64 e x 16 d (d contiguous), store transposed [d][e]
            int dl = tid & 15;
            int el = tid >> 4;      // 0..15
            #pragma unroll
            for (int p = 0; p < 4; p++)
                Bs[dl][el + p * 16] = Wbase[(size_t)(e0 + el + p * 16) * 512 + d0 + dl];
        }
        __syncthreads();
        #pragma unroll
        for (int dd = 0; dd < 16; dd++) {
            float a[4], w[4];
            #pragma unroll
            for (int i = 0; i < 4; i++) a[i] = As[dd][tx * 4 + i];
            #pragma unroll
            for (int j = 0; j < 4; j++) w[j] = Bs[dd][ty * 4 + j];
            #pragma unroll
            for (int i = 0; i < 4; i++)
                #pragma unroll
                for (int j = 0; j < 4; j++)
                    acc[i][j] += a[i] * w[j];
        }
        __syncthreads();
    }
    float* Obase = Qbuf + ((size_t)(sel * 8 + l) * 16 + b) * 98304;
    #pragma unroll
    for (int i = 0; i < 4; i++) {
        int t = t0 + tx * 4 + i;
        #pragma unroll
        for (int j = 0; j < 4; j++) {
            int e = e0 + ty * 4 + j;
            Obase[(size_t)t * 512 + e] = acc[i][j] + b0[l * 512 + e];
        }
    }
}

// ---------------- K2: score volume + fused row/col max ----------------
// per block: one (l, q, k). score[s,t] = (K[k,s,:]·Q[q,t,:]) * sigmoid(se[l,s,t])
// x[l][2j][t]   = max_s score[s,t]
// x[l][2j+1][s] = max_t score[s,t]
__global__ __launch_bounds__(256) void k_score(const float* __restrict__ Qbuf,
                                               const float* __restrict__ se,
                                               float* __restrict__ xbuf) {
    int bid = blockIdx.x;
    int kk = bid & 15; bid >>= 4;
    int qq = bid & 15; bid >>= 4;
    int l  = bid;
    const float* Qb  = Qbuf + ((size_t)(0 * 8 + l) * 16 + qq) * 98304; // [t][d]
    const float* Kb  = Qbuf + ((size_t)(1 * 8 + l) * 16 + kk) * 98304; // [s][d]
    const float* seb = se + (size_t)l * 192 * 192;

    __shared__ float Ks[32][68];     // [d][s]
    __shared__ float Qs[32][68];     // [d][t]
    __shared__ unsigned tkey[192];   // max over s, per t
    __shared__ unsigned skey[192];   // max over t, per s
    int tid = threadIdx.x;
    if (tid < 192) { tkey[tid] = 0u; skey[tid] = 0u; }
    __syncthreads();
    int tx = tid & 15, ty = tid >> 4;

    for (int s0 = 0; s0 < 192; s0 += 64)
    for (int t0 = 0; t0 < 192; t0 += 64) {
        float acc[4][4] = {};
        for (int d0 = 0; d0 < 512; d0 += 32) {
            int dl = tid & 31;
            int rl = tid >> 5;   // 0..7
            #pragma unroll
            for (int p = 0; p < 8; p++) {
                int r = rl + p * 8;
                Ks[dl][r] = Kb[(size_t)(s0 + r) * 512 + d0 + dl];
                Qs[dl][r] = Qb[(size_t)(t0 + r) * 512 + d0 + dl];
            }
            __syncthreads();
            #pragma unroll
            for (int dd = 0; dd < 32; dd++) {
                float a[4], bb[4];
                #pragma unroll
                for (int i = 0; i < 4; i++) a[i]  = Ks[dd][tx * 4 + i];
                #pragma unroll
                for (int j = 0; j < 4; j++) bb[j] = Qs[dd][ty * 4 + j];
                #pragma unroll
                for (int i = 0; i < 4; i++)
                    #pragma unroll
                    for (int j = 0; j < 4; j++)
                        acc[i][j] += a[i] * bb[j];
            }
            __syncthreads();
        }
        // sigmoid mask + local max, then merge into LDS running maxes
        float rowm[4] = {-3.4e38f, -3.4e38f, -3.4e38f, -3.4e38f}; // per s (i)
        float colm[4] = {-3.4e38f, -3.4e38f, -3.4e38f, -3.4e38f}; // per t (j)
        #pragma unroll
        for (int i = 0; i < 4; i++) {
            int s = s0 + tx * 4 + i;
            #pragma unroll
            for (int j = 0; j < 4; j++) {
                int t = t0 + ty * 4 + j;
                float m = seb[s * 192 + t];
                float v = acc[i][j] * (1.f / (1.f + expf(-m)));
                rowm[i] = fmaxf(rowm[i], v);
                colm[j] = fmaxf(colm[j], v);
            }
        }
        #pragma unroll
        for (int i = 0; i < 4; i++) atomicMax(&skey[s0 + tx * 4 + i], fkey(rowm[i]));
        #pragma unroll
        for (int j = 0; j < 4; j++) atomicMax(&tkey[t0 + ty * 4 + j], fkey(colm[j]));
        __syncthreads();
    }
    int jp = qq * 16 + kk;
    float* xb = xbuf + (size_t)l * 512 * 192 + (size_t)(2 * jp) * 192;
    if (tid < 192) {
        xb[tid]       = funkey(tkey[tid]);   // row 2j:   max over s, indexed by t
        xb[192 + tid] = funkey(skey[tid]);   // row 2j+1: max over t, indexed by s
    }
}

// ---------------- K3: bn1 global stats per layer ----------------
__global__ __launch_bounds__(256) void k_bn1stats(const float* __restrict__ xbuf,
                                                  float* __restrict__ bn1s) {
    int l = blockIdx.x;
    const float* xb = xbuf + (size_t)l * 98304;
    int tid = threadIdx.x;
    float s = 0.f, s2 = 0.f;
    for (int i = tid; i < 98304; i += 256) { float v = xb[i]; s += v; s2 += v * v; }
    __shared__ float rs[4], rs2[4];
    int lane = tid & 63, w = tid >> 6;
    #pragma unroll
    for (int o = 32; o; o >>= 1) { s += __shfl_down(s, o); s2 += __shfl_down(s2, o); }
    if (lane == 0) { rs[w] = s; rs2[w] = s2; }
    __syncthreads();
    if (tid == 0) {
        float S1 = rs[0] + rs[1] + rs[2] + rs[3];
        float S2 = rs2[0] + rs2[1] + rs2[2] + rs2[3];
        float mu = S1 * (1.f / 98304.f);
        float var = S2 * (1.f / 98304.f) - mu * mu;
        bn1s[l * 2]     = mu;
        bn1s[l * 2 + 1] = rsqrtf(var + EPS_);
    }
}

// ---------------- K4: fc2 GEMM with bn1 folded into A-load ----------------
// h[l,n,f] = sum_r (a1*x[l,n,r]+c1) * w2[l,f,r] + b2[l,f]
__global__ __launch_bounds__(256) void k_fc2(const float* __restrict__ xbuf,
                                             const float* __restrict__ bn1s,
                                             const float* __restrict__ bn1_g,
                                             const float* __restrict__ bn1_b,
                                             const float* __restrict__ w2,
                                             const float* __restrict__ b2,
                                             float* __restrict__ hbuf) {
    int bid = blockIdx.x;
    int ft = bid & 31; bid >>= 5;   // 32 x 64 f
    int nt = bid & 7;  bid >>= 3;   // 8 x 64 n
    int l  = bid;
    float mean = bn1s[l * 2], rstd = bn1s[l * 2 + 1];
    float a1 = bn1_g[l] * rstd;
    float c1 = bn1_b[l] - mean * a1;
    const float* xb = xbuf + (size_t)l * 98304;
    const float* wb = w2 + (size_t)l * 2048 * 192;
    int n0 = nt * 64, f0 = ft * 64;

    __shared__ float As[16][68];   // [r][n]
    __shared__ float Bs[16][68];   // [r][f]
    int tid = threadIdx.x;
    int tx = tid & 15, ty = tid >> 4;
    float acc[4][4] = {};

    for (int r0 = 0; r0 < 192; r0 += 16) {
        int rl = tid & 15;
        int ol = tid >> 4;   // 0..15
        #pragma unroll
        for (int p = 0; p < 4; p++) {
            As[rl][ol + p * 16] = xb[(size_t)(n0 + ol + p * 16) * 192 + r0 + rl] * a1 + c1;
            Bs[rl][ol + p * 16] = wb[(size_t)(f0 + ol + p * 16) * 192 + r0 + rl];
        }
        __syncthreads();
        #pragma unroll
        for (int dd = 0; dd < 16; dd++) {
            float a[4], w[4];
            #pragma unroll
            for (int i = 0; i < 4; i++) a[i] = As[dd][tx * 4 + i];
            #pragma unroll
            for (int j = 0; j < 4; j++) w[j] = Bs[dd][ty * 4 + j];
            #pragma unroll
            for (int i = 0; i < 4; i++)
                #pragma unroll
                for (int j = 0; j < 4; j++)
                    acc[i][j] += a[i] * w[j];
        }
        __syncthreads();
    }
    float* hb = hbuf + (size_t)l * 512 * 2048;
    #pragma unroll
    for (int i = 0; i < 4; i++) {
        int n = n0 + tx * 4 + i;
        #pragma unroll
        for (int j = 0; j < 4; j++) {
            int f = f0 + ty * 4 + j;
            hb[(size_t)n * 2048 + f] = acc[i][j] + b2[l * 2048 + f];
        }
    }
}

// ---------------- K5: bn2 per-feature stats ----------------
__global__ __launch_bounds__(256) void k_bn2stats(const float* __restrict__ hbuf,
                                                  float* __restrict__ bn2m,
                                                  float* __restrict__ bn2r) {
    int f = (blockIdx.x & 7) * 256 + threadIdx.x;
    int l = blockIdx.x >> 3;
    const float* hb = hbuf + (size_t)l * 512 * 2048 + f;
    float s = 0.f, s2 = 0.f;
    for (int n = 0; n < 512; n++) { float v = hb[(size_t)n * 2048]; s += v; s2 += v * v; }
    float mu = s * (1.f / 512.f);
    float var = s2 * (1.f / 512.f) - mu * mu;
    bn2m[l * 2048 + f] = mu;
    bn2r[l * 2048 + f] = rsqrtf(var + EPS_);
}

// ---------------- K6: bn2 + relu + fc3 dot ----------------
__global__ __launch_bounds__(256) void k_fc3(const float* __restrict__ hbuf,
                                             const float* __restrict__ bn2m,
                                             const float* __restrict__ bn2r,
                                             const float* __restrict__ g2,
                                             const float* __restrict__ bb2,
                                             const float* __restrict__ w3,
                                             const float* __restrict__ b3,
                                             float* __restrict__ ybuf) {
    int n = blockIdx.x & 511;
    int l = blockIdx.x >> 9;
    const float* hb = hbuf + ((size_t)l * 512 + n) * 2048;
    int tid = threadIdx.x;
    float sum = 0.f;
    for (int f = tid; f < 2048; f += 256) {
        float a2 = g2[l * 2048 + f] * bn2r[l * 2048 + f];
        float c2 = bb2[l * 2048 + f] - bn2m[l * 2048 + f] * a2;
        float v = hb[f] * a2 + c2;
        v = fmaxf(v, 0.f);
        sum += v * w3[l * 2048 + f];
    }
    __shared__ float red[4];
    int lane = tid & 63, w = tid >> 6;
    #pragma unroll
    for (int o = 32; o; o >>= 1) sum += __shfl_down(sum, o);
    if (lane == 0) red[w] = sum;
    __syncthreads();
    if (tid == 0) ybuf[l * 512 + n] = red[0] + red[1] + red[2] + red[3] + b3[l];
}

// ---------------- K7: pair-sum + bn3 + layer-sum + pair_labels ----------------
__global__ __launch_bounds__(256) void k_final(const float* __restrict__ ybuf,
                                               const float* __restrict__ g3,
                                               const float* __restrict__ bb3,
                                               const int* __restrict__ targets,
                                               float* __restrict__ out) {
    int tid = threadIdx.x;   // one pair (q*16+k) per thread
    __shared__ float red[8];
    float scoreacc = 0.f;
    for (int l = 0; l < 8; l++) {
        float z = ybuf[l * 512 + 2 * tid] + ybuf[l * 512 + 2 * tid + 1];
        float s = z, s2 = z * z;
        int lane = tid & 63, w = tid >> 6;
        #pragma unroll
        for (int o = 32; o; o >>= 1) { s += __shfl_down(s, o); s2 += __shfl_down(s2, o); }
        if (lane == 0) { red[w] = s; red[4 + w] = s2; }
        __syncthreads();
        float S1 = red[0] + red[1] + red[2] + red[3];
        float S2 = red[4] + red[5] + red[6] + red[7];
        float mu = S1 * (1.f / 256.f);
        float var = S2 * (1.f / 256.f) - mu * mu;
        float rstd = rsqrtf(var + EPS_);
        scoreacc += g3[l] * (z - mu) * rstd + bb3[l];
        __syncthreads();
    }
    out[tid] = scoreacc;
    int i = tid >> 4, j = tid & 15;
    out[256 + tid] = (targets[i] == targets[j]) ? 1.f : 0.f;
}

extern "C" void kernel_launch(void* const* d_in, const int* in_sizes, int n_in,
                              void* d_out, int out_size, void* d_ws, size_t ws_size,
                              hipStream_t stream) {
    const float* q_feat = (const float*)d_in[0];
    const float* g_feat = (const float*)d_in[1];
    const int*   targets = (const int*)d_in[2];
    const float* se     = (const float*)d_in[3];
    const float* fc0_w  = (const float*)d_in[4];
    const float* fc0_b  = (const float*)d_in[5];
    const float* bn1_g  = (const float*)d_in[6];
    const float* bn1_b  = (const float*)d_in[7];
    const float* fc2_w  = (const float*)d_in[8];
    const float* fc2_b  = (const float*)d_in[9];
    const float* bn2_g  = (const float*)d_in[10];
    const float* bn2_b  = (const float*)d_in[11];
    const float* fc3_w  = (const float*)d_in[12];
    const float* fc3_b  = (const float*)d_in[13];
    const float* bn3_g  = (const float*)d_in[14];
    const float* bn3_b  = (const float*)d_in[15];

    float* ws   = (float*)d_ws;
    float* Qbuf = ws;
    float* xbuf = Qbuf + 25165824;
    float* hbuf = xbuf + 786432;
    float* bn1s = hbuf + 8388608;
    float* bn2m = bn1s + 16;
    float* bn2r = bn2m + 16384;
    float* ybuf = bn2r + 16384;
    float* out  = (float*)d_out;

    k_fc0<<<6144, 256, 0, stream>>>(q_feat, g_feat, fc0_w, fc0_b, Qbuf);
    k_score<<<2048, 256, 0, stream>>>(Qbuf, se, xbuf);
    k_bn1stats<<<8, 256, 0, stream>>>(xbuf, bn1s);
    k_fc2<<<2048, 256, 0, stream>>>(xbuf, bn1s, bn1_g, bn1_b, fc2_w, fc2_b, hbuf);
    k_bn2stats<<<64, 256, 0, stream>>>(hbuf, bn2m, bn2r);
    k_fc3<<<4096, 256, 0, stream>>>(hbuf, bn2m, bn2r, bn2_g, bn2_b, fc3_w, fc3_b, ybuf);
    k_final<<<1, 256, 0, stream>>>(ybuf, bn3_g, bn3_b, targets, out);
}

// Round 2
// 909.342 us; speedup vs baseline: 2.1351x; 2.1351x over previous
//
#include <hip/hip_runtime.h>
#include <hip/hip_bf16.h>

// TransMatch round 2: score volume via fp16 MFMA (32x32x16), fp32 elsewhere.
// Workspace layout:
//   Qh    [2][8][16][192][512] fp16 = 25,165,824 halfs (50.3 MB)
//   xbuf  [8][512][192] f32
//   hbuf  [8][512][2048] f32
//   bn1s / bn2m / bn2r / ybuf f32
// total ~87 MB.

#define EPS_ 1e-5f

typedef __attribute__((ext_vector_type(8))) _Float16 fp16x8;
typedef __attribute__((ext_vector_type(16))) float f32x16;

__device__ __forceinline__ unsigned fkey(float f) {
    unsigned u = __float_as_uint(f);
    return (u & 0x80000000u) ? ~u : (u | 0x80000000u);
}
__device__ __forceinline__ float funkey(unsigned k) {
    return (k & 0x80000000u) ? __uint_as_float(k & 0x7FFFFFFFu)
                             : __uint_as_float(~k);
}

// ---------------- K1: fc0 projection (query & key), fp32 compute, fp16 out ----
__global__ __launch_bounds__(256) void k_fc0(const float* __restrict__ qfeat,
                                             const float* __restrict__ gfeat,
                                             const float* __restrict__ w0,
                                             const float* __restrict__ b0,
                                             _Float16* __restrict__ Qh) {
    int bid = blockIdx.x;
    int et = bid & 7;  bid >>= 3;
    int tt = bid % 3;  bid /= 3;
    int b  = bid & 15; bid >>= 4;
    int l  = bid & 7;  bid >>= 3;
    int sel = bid;
    const float* feat  = sel ? gfeat : qfeat;
    const float* Abase = feat + (size_t)b * 4096 * 192 + (size_t)l * 512 * 192;
    const float* Wbase = w0 + (size_t)l * 512 * 512;
    int t0 = tt * 64, e0 = et * 64;

    __shared__ float As[16][68];
    __shared__ float Bs[16][68];
    int tid = threadIdx.x;
    int tx = tid & 15, ty = tid >> 4;
    float acc[4][4] = {};

    for (int d0 = 0; d0 < 512; d0 += 16) {
        {
            int dl = tid >> 6;
            int tl = tid & 63;
            #pragma unroll
            for (int p = 0; p < 4; p++)
                As[dl + p * 4][tl] = Abase[(size_t)(d0 + dl + p * 4) * 192 + t0 + tl];
        }
        {
            int dl = tid & 15;
            int el = tid >> 4;
            #pragma unroll
            for (int p = 0; p < 4; p++)
                Bs[dl][el + p * 16] = Wbase[(size_t)(e0 + el + p * 16) * 512 + d0 + dl];
        }
        __syncthreads();
        #pragma unroll
        for (int dd = 0; dd < 16; dd++) {
            float a[4], w[4];
            #pragma unroll
            for (int i = 0; i < 4; i++) a[i] = As[dd][tx * 4 + i];
            #pragma unroll
            for (int j = 0; j < 4; j++) w[j] = Bs[dd][ty * 4 + j];
            #pragma unroll
            for (int i = 0; i < 4; i++)
                #pragma unroll
                for (int j = 0; j < 4; j++)
                    acc[i][j] += a[i] * w[j];
        }
        __syncthreads();
    }
    _Float16* Obase = Qh + ((size_t)(sel * 8 + l) * 16 + b) * 98304;
    #pragma unroll
    for (int i = 0; i < 4; i++) {
        int t = t0 + tx * 4 + i;
        #pragma unroll
        for (int j = 0; j < 4; j++) {
            int e = e0 + ty * 4 + j;
            Obase[(size_t)t * 512 + e] = (_Float16)(acc[i][j] + b0[l * 512 + e]);
        }
    }
}

// ---------------- K2: score volume via MFMA + fused row/col max ----------------
// Block: 384 threads = 6 waves; one (l,q,k) per block; full 192x192 output.
// Wave w owns s-rows [w*32, w*32+32); 6 n-tiles of 32 t-columns each.
// LDS row stride 80 B (32 d fp16 + 16 B pad) -> aggregate conflict-free b128.
__global__ __launch_bounds__(384) void k_score(const _Float16* __restrict__ Qh,
                                               const float* __restrict__ se,
                                               float* __restrict__ xbuf) {
    int bid = blockIdx.x;
    int kk = bid & 15; bid >>= 4;
    int qq = bid & 15; bid >>= 4;
    int l  = bid;
    const _Float16* Qb = Qh + ((size_t)(0 * 8 + l) * 16 + qq) * 98304; // [t][d]
    const _Float16* Kb = Qh + ((size_t)(1 * 8 + l) * 16 + kk) * 98304; // [s][d]
    const float* seb = se + (size_t)l * 36864;

    __shared__ __align__(16) char lds[2 * 192 * 80];   // K tile | Q tile
    __shared__ unsigned tkey[192];
    __shared__ unsigned skey[192];
    char* Kt = lds;
    char* Qt = lds + 192 * 80;

    int tid = threadIdx.x;
    int lane = tid & 63;
    int w = tid >> 6;          // wave id 0..5 = m-tile
    int half = lane >> 5;      // MFMA k-half
    int lrow = lane & 31;
    if (tid < 192) { tkey[tid] = 0u; skey[tid] = 0u; }

    f32x16 acc[6];
    #pragma unroll
    for (int t = 0; t < 6; t++)
        #pragma unroll
        for (int i = 0; i < 16; i++) acc[t][i] = 0.f;

    for (int d0 = 0; d0 < 512; d0 += 32) {
        __syncthreads();   // previous reads done before overwrite (also covers key init)
        // stage 192 rows x 32 d of K and Q: 768 16B-slots per matrix, 2 per thread
        #pragma unroll
        for (int p = 0; p < 2; p++) {
            int slot = tid + p * 384;
            int q4 = slot & 3;
            int row = slot >> 2;           // 0..191
            const uint4 kv = *(const uint4*)(Kb + (size_t)row * 512 + d0 + q4 * 8);
            *(uint4*)(Kt + row * 80 + q4 * 16) = kv;
            const uint4 qv = *(const uint4*)(Qb + (size_t)row * 512 + d0 + q4 * 8);
            *(uint4*)(Qt + row * 80 + q4 * 16) = qv;
        }
        __syncthreads();
        #pragma unroll
        for (int ks = 0; ks < 2; ks++) {
            fp16x8 a = *(const fp16x8*)(Kt + (w * 32 + lrow) * 80 + ks * 32 + half * 16);
            #pragma unroll
            for (int tn = 0; tn < 6; tn++) {
                fp16x8 bfr = *(const fp16x8*)(Qt + (tn * 32 + lrow) * 80 + ks * 32 + half * 16);
                acc[tn] = __builtin_amdgcn_mfma_f32_32x32x16_f16(a, bfr, acc[tn], 0, 0, 0);
            }
        }
    }
    __syncthreads();

    // epilogue: sigmoid mask + row/col max
    float srun[16];
    #pragma unroll
    for (int r = 0; r < 16; r++) srun[r] = -3.4e38f;
    #pragma unroll
    for (int tn = 0; tn < 6; tn++) {
        int t = tn * 32 + lrow;
        float tm = -3.4e38f;
        #pragma unroll
        for (int r = 0; r < 16; r++) {
            int s = w * 32 + (r & 3) + 8 * (r >> 2) + 4 * half;
            float m = seb[(size_t)s * 192 + t];
            float v = acc[tn][r] * (1.f / (1.f + __expf(-m)));
            tm = fmaxf(tm, v);
            srun[r] = fmaxf(srun[r], v);
        }
        tm = fmaxf(tm, __shfl_xor(tm, 32));
        if (half == 0) atomicMax(&tkey[t], fkey(tm));
    }
    #pragma unroll
    for (int r = 0; r < 16; r++) {
        int s = w * 32 + (r & 3) + 8 * (r >> 2) + 4 * half;
        atomicMax(&skey[s], fkey(srun[r]));
    }
    __syncthreads();

    int jp = qq * 16 + kk;
    float* xb = xbuf + (size_t)l * 98304 + (size_t)(2 * jp) * 192;
    if (tid < 192) {
        xb[tid]       = funkey(tkey[tid]);   // row 2j:   max over s, indexed by t
        xb[192 + tid] = funkey(skey[tid]);   // row 2j+1: max over t, indexed by s
    }
}

// ---------------- K3: bn1 global stats per layer ----------------
__global__ __launch_bounds__(256) void k_bn1stats(const float* __restrict__ xbuf,
                                                  float* __restrict__ bn1s) {
    int l = blockIdx.x;
    const float* xb = xbuf + (size_t)l * 98304;
    int tid = threadIdx.x;
    float s = 0.f, s2 = 0.f;
    for (int i = tid; i < 98304; i += 256) { float v = xb[i]; s += v; s2 += v * v; }
    __shared__ float rs[4], rs2[4];
    int lane = tid & 63, w = tid >> 6;
    #pragma unroll
    for (int o = 32; o; o >>= 1) { s += __shfl_down(s, o); s2 += __shfl_down(s2, o); }
    if (lane == 0) { rs[w] = s; rs2[w] = s2; }
    __syncthreads();
    if (tid == 0) {
        float S1 = rs[0] + rs[1] + rs[2] + rs[3];
        float S2 = rs2[0] + rs2[1] + rs2[2] + rs2[3];
        float mu = S1 * (1.f / 98304.f);
        float var = S2 * (1.f / 98304.f) - mu * mu;
        bn1s[l * 2]     = mu;
        bn1s[l * 2 + 1] = rsqrtf(var + EPS_);
    }
}

// ---------------- K4: fc2 GEMM with bn1 folded into A-load ----------------
__global__ __launch_bounds__(256) void k_fc2(const float* __restrict__ xbuf,
                                             const float* __restrict__ bn1s,
                                             const float* __restrict__ bn1_g,
                                             const float* __restrict__ bn1_b,
                                             const float* __restrict__ w2,
                                             const float* __restrict__ b2,
                                             float* __restrict__ hbuf) {
    int bid = blockIdx.x;
    int ft = bid & 31; bid >>= 5;
    int nt = bid & 7;  bid >>= 3;
    int l  = bid;
    float mean = bn1s[l * 2], rstd = bn1s[l * 2 + 1];
    float a1 = bn1_g[l] * rstd;
    float c1 = bn1_b[l] - mean * a1;
    const float* xb = xbuf + (size_t)l * 98304;
    const float* wb = w2 + (size_t)l * 2048 * 192;
    int n0 = nt * 64, f0 = ft * 64;

    __shared__ float As[16][68];
    __shared__ float Bs[16][68];
    int tid = threadIdx.x;
    int tx = tid & 15, ty = tid >> 4;
    float acc[4][4] = {};

    for (int r0 = 0; r0 < 192; r0 += 16) {
        int rl = tid & 15;
        int ol = tid >> 4;
        #pragma unroll
        for (int p = 0; p < 4; p++) {
            As[rl][ol + p * 16] = xb[(size_t)(n0 + ol + p * 16) * 192 + r0 + rl] * a1 + c1;
            Bs[rl][ol + p * 16] = wb[(size_t)(f0 + ol + p * 16) * 192 + r0 + rl];
        }
        __syncthreads();
        #pragma unroll
        for (int dd = 0; dd < 16; dd++) {
            float a[4], wv[4];
            #pragma unroll
            for (int i = 0; i < 4; i++) a[i] = As[dd][tx * 4 + i];
            #pragma unroll
            for (int j = 0; j < 4; j++) wv[j] = Bs[dd][ty * 4 + j];
            #pragma unroll
            for (int i = 0; i < 4; i++)
                #pragma unroll
                for (int j = 0; j < 4; j++)
                    acc[i][j] += a[i] * wv[j];
        }
        __syncthreads();
    }
    float* hb = hbuf + (size_t)l * 512 * 2048;
    #pragma unroll
    for (int i = 0; i < 4; i++) {
        int n = n0 + tx * 4 + i;
        #pragma unroll
        for (int j = 0; j < 4; j++) {
            int f = f0 + ty * 4 + j;
            hb[(size_t)n * 2048 + f] = acc[i][j] + b2[l * 2048 + f];
        }
    }
}

// ---------------- K5: bn2 per-feature stats ----------------
__global__ __launch_bounds__(256) void k_bn2stats(const float* __restrict__ hbuf,
                                                  float* __restrict__ bn2m,
                                                  float* __restrict__ bn2r) {
    int f = (blockIdx.x & 7) * 256 + threadIdx.x;
    int l = blockIdx.x >> 3;
    const float* hb = hbuf + (size_t)l * 512 * 2048 + f;
    float s = 0.f, s2 = 0.f;
    for (int n = 0; n < 512; n++) { float v = hb[(size_t)n * 2048]; s += v; s2 += v * v; }
    float mu = s * (1.f / 512.f);
    float var = s2 * (1.f / 512.f) - mu * mu;
    bn2m[l * 2048 + f] = mu;
    bn2r[l * 2048 + f] = rsqrtf(var + EPS_);
}

// ---------------- K6: bn2 + relu + fc3 dot ----------------
__global__ __launch_bounds__(256) void k_fc3(const float* __restrict__ hbuf,
                                             const float* __restrict__ bn2m,
                                             const float* __restrict__ bn2r,
                                             const float* __restrict__ g2,
                                             const float* __restrict__ bb2,
                                             const float* __restrict__ w3,
                                             const float* __restrict__ b3,
                                             float* __restrict__ ybuf) {
    int n = blockIdx.x & 511;
    int l = blockIdx.x >> 9;
    const float* hb = hbuf + ((size_t)l * 512 + n) * 2048;
    int tid = threadIdx.x;
    float sum = 0.f;
    for (int f = tid; f < 2048; f += 256) {
        float a2 = g2[l * 2048 + f] * bn2r[l * 2048 + f];
        float c2 = bb2[l * 2048 + f] - bn2m[l * 2048 + f] * a2;
        float v = hb[f] * a2 + c2;
        v = fmaxf(v, 0.f);
        sum += v * w3[l * 2048 + f];
    }
    __shared__ float red[4];
    int lane = tid & 63, w = tid >> 6;
    #pragma unroll
    for (int o = 32; o; o >>= 1) sum += __shfl_down(sum, o);
    if (lane == 0) red[w] = sum;
    __syncthreads();
    if (tid == 0) ybuf[l * 512 + n] = red[0] + red[1] + red[2] + red[3] + b3[l];
}

// ---------------- K7: pair-sum + bn3 + layer-sum + pair_labels ----------------
__global__ __launch_bounds__(256) void k_final(const float* __restrict__ ybuf,
                                               const float* __restrict__ g3,
                                               const float* __restrict__ bb3,
                                               const int* __restrict__ targets,
                                               float* __restrict__ out) {
    int tid = threadIdx.x;
    __shared__ float red[8];
    float scoreacc = 0.f;
    for (int l = 0; l < 8; l++) {
        float z = ybuf[l * 512 + 2 * tid] + ybuf[l * 512 + 2 * tid + 1];
        float s = z, s2 = z * z;
        int lane = tid & 63, w = tid >> 6;
        #pragma unroll
        for (int o = 32; o; o >>= 1) { s += __shfl_down(s, o); s2 += __shfl_down(s2, o); }
        if (lane == 0) { red[w] = s; red[4 + w] = s2; }
        __syncthreads();
        float S1 = red[0] + red[1] + red[2] + red[3];
        float S2 = red[4] + red[5] + red[6] + red[7];
        float mu = S1 * (1.f / 256.f);
        float var = S2 * (1.f / 256.f) - mu * mu;
        float rstd = rsqrtf(var + EPS_);
        scoreacc += g3[l] * (z - mu) * rstd + bb3[l];
        __syncthreads();
    }
    out[tid] = scoreacc;
    int i = tid >> 4, j = tid & 15;
    out[256 + tid] = (targets[i] == targets[j]) ? 1.f : 0.f;
}

extern "C" void kernel_launch(void* const* d_in, const int* in_sizes, int n_in,
                              void* d_out, int out_size, void* d_ws, size_t ws_size,
                              hipStream_t stream) {
    const float* q_feat = (const float*)d_in[0];
    const float* g_feat = (const float*)d_in[1];
    const int*   targets = (const int*)d_in[2];
    const float* se     = (const float*)d_in[3];
    const float* fc0_w  = (const float*)d_in[4];
    const float* fc0_b  = (const float*)d_in[5];
    const float* bn1_g  = (const float*)d_in[6];
    const float* bn1_b  = (const float*)d_in[7];
    const float* fc2_w  = (const float*)d_in[8];
    const float* fc2_b  = (const float*)d_in[9];
    const float* bn2_g  = (const float*)d_in[10];
    const float* bn2_b  = (const float*)d_in[11];
    const float* fc3_w  = (const float*)d_in[12];
    const float* fc3_b  = (const float*)d_in[13];
    const float* bn3_g  = (const float*)d_in[14];
    const float* bn3_b  = (const float*)d_in[15];

    float* ws   = (float*)d_ws;
    _Float16* Qh = (_Float16*)ws;                 // 25,165,824 halfs
    float* xbuf = ws + 12582912;
    float* hbuf = xbuf + 786432;
    float* bn1s = hbuf + 8388608;
    float* bn2m = bn1s + 16;
    float* bn2r = bn2m + 16384;
    float* ybuf = bn2r + 16384;
    float* out  = (float*)d_out;

    k_fc0<<<6144, 256, 0, stream>>>(q_feat, g_feat, fc0_w, fc0_b, Qh);
    k_score<<<2048, 384, 0, stream>>>(Qh, se, xbuf);
    k_bn1stats<<<8, 256, 0, stream>>>(xbuf, bn1s);
    k_fc2<<<2048, 256, 0, stream>>>(xbuf, bn1s, bn1_g, bn1_b, fc2_w, fc2_b, hbuf);
    k_bn2stats<<<64, 256, 0, stream>>>(hbuf, bn2m, bn2r);
    k_fc3<<<4096, 256, 0, stream>>>(hbuf, bn2m, bn2r, bn2_g, bn2_b, fc3_w, fc3_b, ybuf);
    k_final<<<1, 256, 0, stream>>>(ybuf, bn3_g, bn3_b, targets, out);
}

// Round 3
// 661.296 us; speedup vs baseline: 2.9359x; 1.3751x over previous
//
#include <hip/hip_runtime.h>
#include <hip/hip_bf16.h>

// TransMatch round 3: fc0 moved to fp16 MFMA (fused fp32->fp16 staging).
// Workspace layout:
//   Qh    [2][8][16][192][512] fp16 = 25,165,824 halfs (50.3 MB)
//   xbuf  [8][512][192] f32
//   hbuf  [8][512][2048] f32
//   bn1s / bn2m / bn2r / ybuf f32

#define EPS_ 1e-5f

typedef __attribute__((ext_vector_type(8))) _Float16 fp16x8;
typedef __attribute__((ext_vector_type(16))) float f32x16;

__device__ __forceinline__ unsigned fkey(float f) {
    unsigned u = __float_as_uint(f);
    return (u & 0x80000000u) ? ~u : (u | 0x80000000u);
}
__device__ __forceinline__ float funkey(unsigned k) {
    return (k & 0x80000000u) ? __uint_as_float(k & 0x7FFFFFFFu)
                             : __uint_as_float(~k);
}

// ---------------- K1: fc0 via MFMA ----------------
// Per block: one (sel, l, b, t-tile 64, e-tile 256). K=512 in chunks of 32.
// A = feat (memory [d][t], t contig) -> LDS At[t][d] fp16 (transpose via b16 writes).
// B = w0   (memory [e][d], d contig) -> LDS Bt[e][d] fp16 (direct convert).
// 4 waves; wave w owns e columns [w*64, w*64+64) as 2 n-subtiles; m = 64 t as 2 subtiles.
__global__ __launch_bounds__(256) void k_fc0(const float* __restrict__ qfeat,
                                             const float* __restrict__ gfeat,
                                             const float* __restrict__ w0,
                                             const float* __restrict__ b0,
                                             _Float16* __restrict__ Qh) {
    int bid = blockIdx.x;
    int et = bid & 1;  bid >>= 1;
    int tt = bid % 3;  bid /= 3;
    int b  = bid & 15; bid >>= 4;
    int l  = bid & 7;  bid >>= 3;
    int sel = bid;
    const float* feat  = sel ? gfeat : qfeat;
    const float* Af = feat + (size_t)b * 4096 * 192 + (size_t)l * 512 * 192;
    const float* Wf = w0 + (size_t)l * 262144;
    int t0 = tt * 64, e0 = et * 256;

    __shared__ __align__(16) char At[64 * 80];    // row t: 32 fp16 (64B) + 16B pad
    __shared__ __align__(16) char Bt[256 * 80];   // row e: 32 fp16 + pad

    int tid = threadIdx.x;
    int lane = tid & 63;
    int w = tid >> 6;
    int half = lane >> 5;
    int lrow = lane & 31;

    f32x16 acc[2][2];
    #pragma unroll
    for (int mi = 0; mi < 2; mi++)
        #pragma unroll
        for (int ni = 0; ni < 2; ni++)
            #pragma unroll
            for (int r = 0; r < 16; r++) acc[mi][ni][r] = 0.f;

    for (int d0 = 0; d0 < 512; d0 += 32) {
        __syncthreads();
        {   // A: 32 d rows x 64 t, lane = t (coalesced fp32), scatter b16 to At[t][d]
            int tA = tid & 63;
            int dA = tid >> 6;   // 0..3
            #pragma unroll
            for (int r = 0; r < 8; r++) {
                int d = dA + r * 4;
                float v = Af[(size_t)(d0 + d) * 192 + t0 + tA];
                *(_Float16*)(At + tA * 80 + d * 2) = (_Float16)v;
            }
        }
        {   // B: 256 e rows x 32 d, float4 reads, fp16x4 writes
            #pragma unroll
            for (int p = 0; p < 8; p++) {
                int s = tid + p * 256;
                int e = s >> 3;
                int q = s & 7;
                float4 wv = *(const float4*)(Wf + (size_t)(e0 + e) * 512 + d0 + q * 4);
                _Float16 h[4] = {(_Float16)wv.x, (_Float16)wv.y, (_Float16)wv.z, (_Float16)wv.w};
                *(uint2*)(Bt + e * 80 + q * 8) = *(uint2*)h;
            }
        }
        __syncthreads();
        #pragma unroll
        for (int ks = 0; ks < 2; ks++) {
            int koff = ks * 32 + half * 16;
            fp16x8 a[2], bf[2];
            #pragma unroll
            for (int mi = 0; mi < 2; mi++)
                a[mi] = *(const fp16x8*)(At + (mi * 32 + lrow) * 80 + koff);
            #pragma unroll
            for (int ni = 0; ni < 2; ni++)
                bf[ni] = *(const fp16x8*)(Bt + (w * 64 + ni * 32 + lrow) * 80 + koff);
            #pragma unroll
            for (int mi = 0; mi < 2; mi++)
                #pragma unroll
                for (int ni = 0; ni < 2; ni++)
                    acc[mi][ni] = __builtin_amdgcn_mfma_f32_32x32x16_f16(a[mi], bf[ni], acc[mi][ni], 0, 0, 0);
        }
    }

    _Float16* Obase = Qh + ((size_t)(sel * 8 + l) * 16 + b) * 98304;
    int col = lrow;
    #pragma unroll
    for (int ni = 0; ni < 2; ni++) {
        int e = e0 + w * 64 + ni * 32 + col;
        float bias = b0[l * 512 + e];
        #pragma unroll
        for (int mi = 0; mi < 2; mi++) {
            #pragma unroll
            for (int r = 0; r < 16; r++) {
                int t = t0 + mi * 32 + (r & 3) + 8 * (r >> 2) + 4 * half;
                Obase[(size_t)t * 512 + e] = (_Float16)(acc[mi][ni][r] + bias);
            }
        }
    }
}

// ---------------- K2: score volume via MFMA + fused row/col max ----------------
__global__ __launch_bounds__(384) void k_score(const _Float16* __restrict__ Qh,
                                               const float* __restrict__ se,
                                               float* __restrict__ xbuf) {
    int bid = blockIdx.x;
    int kk = bid & 15; bid >>= 4;
    int qq = bid & 15; bid >>= 4;
    int l  = bid;
    const _Float16* Qb = Qh + ((size_t)(0 * 8 + l) * 16 + qq) * 98304; // [t][d]
    const _Float16* Kb = Qh + ((size_t)(1 * 8 + l) * 16 + kk) * 98304; // [s][d]
    const float* seb = se + (size_t)l * 36864;

    __shared__ __align__(16) char lds[2 * 192 * 80];
    __shared__ unsigned tkey[192];
    __shared__ unsigned skey[192];
    char* Kt = lds;
    char* Qt = lds + 192 * 80;

    int tid = threadIdx.x;
    int lane = tid & 63;
    int w = tid >> 6;
    int half = lane >> 5;
    int lrow = lane & 31;
    if (tid < 192) { tkey[tid] = 0u; skey[tid] = 0u; }

    f32x16 acc[6];
    #pragma unroll
    for (int t = 0; t < 6; t++)
        #pragma unroll
        for (int i = 0; i < 16; i++) acc[t][i] = 0.f;

    for (int d0 = 0; d0 < 512; d0 += 32) {
        __syncthreads();
        #pragma unroll
        for (int p = 0; p < 2; p++) {
            int slot = tid + p * 384;
            int q4 = slot & 3;
            int row = slot >> 2;
            const uint4 kv = *(const uint4*)(Kb + (size_t)row * 512 + d0 + q4 * 8);
            *(uint4*)(Kt + row * 80 + q4 * 16) = kv;
            const uint4 qv = *(const uint4*)(Qb + (size_t)row * 512 + d0 + q4 * 8);
            *(uint4*)(Qt + row * 80 + q4 * 16) = qv;
        }
        __syncthreads();
        #pragma unroll
        for (int ks = 0; ks < 2; ks++) {
            fp16x8 a = *(const fp16x8*)(Kt + (w * 32 + lrow) * 80 + ks * 32 + half * 16);
            #pragma unroll
            for (int tn = 0; tn < 6; tn++) {
                fp16x8 bfr = *(const fp16x8*)(Qt + (tn * 32 + lrow) * 80 + ks * 32 + half * 16);
                acc[tn] = __builtin_amdgcn_mfma_f32_32x32x16_f16(a, bfr, acc[tn], 0, 0, 0);
            }
        }
    }
    __syncthreads();

    float srun[16];
    #pragma unroll
    for (int r = 0; r < 16; r++) srun[r] = -3.4e38f;
    #pragma unroll
    for (int tn = 0; tn < 6; tn++) {
        int t = tn * 32 + lrow;
        float tm = -3.4e38f;
        #pragma unroll
        for (int r = 0; r < 16; r++) {
            int s = w * 32 + (r & 3) + 8 * (r >> 2) + 4 * half;
            float m = seb[(size_t)s * 192 + t];
            float v = acc[tn][r] * (1.f / (1.f + __expf(-m)));
            tm = fmaxf(tm, v);
            srun[r] = fmaxf(srun[r], v);
        }
        tm = fmaxf(tm, __shfl_xor(tm, 32));
        if (half == 0) atomicMax(&tkey[t], fkey(tm));
    }
    #pragma unroll
    for (int r = 0; r < 16; r++) {
        int s = w * 32 + (r & 3) + 8 * (r >> 2) + 4 * half;
        atomicMax(&skey[s], fkey(srun[r]));
    }
    __syncthreads();

    int jp = qq * 16 + kk;
    float* xb = xbuf + (size_t)l * 98304 + (size_t)(2 * jp) * 192;
    if (tid < 192) {
        xb[tid]       = funkey(tkey[tid]);
        xb[192 + tid] = funkey(skey[tid]);
    }
}

// ---------------- K3: bn1 global stats per layer ----------------
__global__ __launch_bounds__(256) void k_bn1stats(const float* __restrict__ xbuf,
                                                  float* __restrict__ bn1s) {
    int l = blockIdx.x;
    const float* xb = xbuf + (size_t)l * 98304;
    int tid = threadIdx.x;
    float s = 0.f, s2 = 0.f;
    for (int i = tid; i < 98304; i += 256) { float v = xb[i]; s += v; s2 += v * v; }
    __shared__ float rs[4], rs2[4];
    int lane = tid & 63, w = tid >> 6;
    #pragma unroll
    for (int o = 32; o; o >>= 1) { s += __shfl_down(s, o); s2 += __shfl_down(s2, o); }
    if (lane == 0) { rs[w] = s; rs2[w] = s2; }
    __syncthreads();
    if (tid == 0) {
        float S1 = rs[0] + rs[1] + rs[2] + rs[3];
        float S2 = rs2[0] + rs2[1] + rs2[2] + rs2[3];
        float mu = S1 * (1.f / 98304.f);
        float var = S2 * (1.f / 98304.f) - mu * mu;
        bn1s[l * 2]     = mu;
        bn1s[l * 2 + 1] = rsqrtf(var + EPS_);
    }
}

// ---------------- K4: fc2 GEMM with bn1 folded into A-load ----------------
__global__ __launch_bounds__(256) void k_fc2(const float* __restrict__ xbuf,
                                             const float* __restrict__ bn1s,
                                             const float* __restrict__ bn1_g,
                                             const float* __restrict__ bn1_b,
                                             const float* __restrict__ w2,
                                             const float* __restrict__ b2,
                                             float* __restrict__ hbuf) {
    int bid = blockIdx.x;
    int ft = bid & 31; bid >>= 5;
    int nt = bid & 7;  bid >>= 3;
    int l  = bid;
    float mean = bn1s[l * 2], rstd = bn1s[l * 2 + 1];
    float a1 = bn1_g[l] * rstd;
    float c1 = bn1_b[l] - mean * a1;
    const float* xb = xbuf + (size_t)l * 98304;
    const float* wb = w2 + (size_t)l * 2048 * 192;
    int n0 = nt * 64, f0 = ft * 64;

    __shared__ float As[16][68];
    __shared__ float Bs[16][68];
    int tid = threadIdx.x;
    int tx = tid & 15, ty = tid >> 4;
    float acc[4][4] = {};

    for (int r0 = 0; r0 < 192; r0 += 16) {
        int rl = tid & 15;
        int ol = tid >> 4;
        #pragma unroll
        for (int p = 0; p < 4; p++) {
            As[rl][ol + p * 16] = xb[(size_t)(n0 + ol + p * 16) * 192 + r0 + rl] * a1 + c1;
            Bs[rl][ol + p * 16] = wb[(size_t)(f0 + ol + p * 16) * 192 + r0 + rl];
        }
        __syncthreads();
        #pragma unroll
        for (int dd = 0; dd < 16; dd++) {
            float a[4], wv[4];
            #pragma unroll
            for (int i = 0; i < 4; i++) a[i] = As[dd][tx * 4 + i];
            #pragma unroll
            for (int j = 0; j < 4; j++) wv[j] = Bs[dd][ty * 4 + j];
            #pragma unroll
            for (int i = 0; i < 4; i++)
                #pragma unroll
                for (int j = 0; j < 4; j++)
                    acc[i][j] += a[i] * wv[j];
        }
        __syncthreads();
    }
    float* hb = hbuf + (size_t)l * 512 * 2048;
    #pragma unroll
    for (int i = 0; i < 4; i++) {
        int n = n0 + tx * 4 + i;
        #pragma unroll
        for (int j = 0; j < 4; j++) {
            int f = f0 + ty * 4 + j;
            hb[(size_t)n * 2048 + f] = acc[i][j] + b2[l * 2048 + f];
        }
    }
}

// ---------------- K5: bn2 per-feature stats ----------------
__global__ __launch_bounds__(256) void k_bn2stats(const float* __restrict__ hbuf,
                                                  float* __restrict__ bn2m,
                                                  float* __restrict__ bn2r) {
    int f = (blockIdx.x & 7) * 256 + threadIdx.x;
    int l = blockIdx.x >> 3;
    const float* hb = hbuf + (size_t)l * 512 * 2048 + f;
    float s = 0.f, s2 = 0.f;
    for (int n = 0; n < 512; n++) { float v = hb[(size_t)n * 2048]; s += v; s2 += v * v; }
    float mu = s * (1.f / 512.f);
    float var = s2 * (1.f / 512.f) - mu * mu;
    bn2m[l * 2048 + f] = mu;
    bn2r[l * 2048 + f] = rsqrtf(var + EPS_);
}

// ---------------- K6: bn2 + relu + fc3 dot ----------------
__global__ __launch_bounds__(256) void k_fc3(const float* __restrict__ hbuf,
                                             const float* __restrict__ bn2m,
                                             const float* __restrict__ bn2r,
                                             const float* __restrict__ g2,
                                             const float* __restrict__ bb2,
                                             const float* __restrict__ w3,
                                             const float* __restrict__ b3,
                                             float* __restrict__ ybuf) {
    int n = blockIdx.x & 511;
    int l = blockIdx.x >> 9;
    const float* hb = hbuf + ((size_t)l * 512 + n) * 2048;
    int tid = threadIdx.x;
    float sum = 0.f;
    for (int f = tid; f < 2048; f += 256) {
        float a2 = g2[l * 2048 + f] * bn2r[l * 2048 + f];
        float c2 = bb2[l * 2048 + f] - bn2m[l * 2048 + f] * a2;
        float v = hb[f] * a2 + c2;
        v = fmaxf(v, 0.f);
        sum += v * w3[l * 2048 + f];
    }
    __shared__ float red[4];
    int lane = tid & 63, w = tid >> 6;
    #pragma unroll
    for (int o = 32; o; o >>= 1) sum += __shfl_down(sum, o);
    if (lane == 0) red[w] = sum;
    __syncthreads();
    if (tid == 0) ybuf[l * 512 + n] = red[0] + red[1] + red[2] + red[3] + b3[l];
}

// ---------------- K7: pair-sum + bn3 + layer-sum + pair_labels ----------------
__global__ __launch_bounds__(256) void k_final(const float* __restrict__ ybuf,
                                               const float* __restrict__ g3,
                                               const float* __restrict__ bb3,
                                               const int* __restrict__ targets,
                                               float* __restrict__ out) {
    int tid = threadIdx.x;
    __shared__ float red[8];
    float scoreacc = 0.f;
    for (int l = 0; l < 8; l++) {
        float z = ybuf[l * 512 + 2 * tid] + ybuf[l * 512 + 2 * tid + 1];
        float s = z, s2 = z * z;
        int lane = tid & 63, w = tid >> 6;
        #pragma unroll
        for (int o = 32; o; o >>= 1) { s += __shfl_down(s, o); s2 += __shfl_down(s2, o); }
        if (lane == 0) { red[w] = s; red[4 + w] = s2; }
        __syncthreads();
        float S1 = red[0] + red[1] + red[2] + red[3];
        float S2 = red[4] + red[5] + red[6] + red[7];
        float mu = S1 * (1.f / 256.f);
        float var = S2 * (1.f / 256.f) - mu * mu;
        float rstd = rsqrtf(var + EPS_);
        scoreacc += g3[l] * (z - mu) * rstd + bb3[l];
        __syncthreads();
    }
    out[tid] = scoreacc;
    int i = tid >> 4, j = tid & 15;
    out[256 + tid] = (targets[i] == targets[j]) ? 1.f : 0.f;
}

extern "C" void kernel_launch(void* const* d_in, const int* in_sizes, int n_in,
                              void* d_out, int out_size, void* d_ws, size_t ws_size,
                              hipStream_t stream) {
    const float* q_feat = (const float*)d_in[0];
    const float* g_feat = (const float*)d_in[1];
    const int*   targets = (const int*)d_in[2];
    const float* se     = (const float*)d_in[3];
    const float* fc0_w  = (const float*)d_in[4];
    const float* fc0_b  = (const float*)d_in[5];
    const float* bn1_g  = (const float*)d_in[6];
    const float* bn1_b  = (const float*)d_in[7];
    const float* fc2_w  = (const float*)d_in[8];
    const float* fc2_b  = (const float*)d_in[9];
    const float* bn2_g  = (const float*)d_in[10];
    const float* bn2_b  = (const float*)d_in[11];
    const float* fc3_w  = (const float*)d_in[12];
    const float* fc3_b  = (const float*)d_in[13];
    const float* bn3_g  = (const float*)d_in[14];
    const float* bn3_b  = (const float*)d_in[15];

    float* ws   = (float*)d_ws;
    _Float16* Qh = (_Float16*)ws;
    float* xbuf = ws + 12582912;
    float* hbuf = xbuf + 786432;
    float* bn1s = hbuf + 8388608;
    float* bn2m = bn1s + 16;
    float* bn2r = bn2m + 16384;
    float* ybuf = bn2r + 16384;
    float* out  = (float*)d_out;

    k_fc0<<<1536, 256, 0, stream>>>(q_feat, g_feat, fc0_w, fc0_b, Qh);
    k_score<<<2048, 384, 0, stream>>>(Qh, se, xbuf);
    k_bn1stats<<<8, 256, 0, stream>>>(xbuf, bn1s);
    k_fc2<<<2048, 256, 0, stream>>>(xbuf, bn1s, bn1_g, bn1_b, fc2_w, fc2_b, hbuf);
    k_bn2stats<<<64, 256, 0, stream>>>(hbuf, bn2m, bn2r);
    k_fc3<<<4096, 256, 0, stream>>>(hbuf, bn2m, bn2r, bn2_g, bn2_b, fc3_w, fc3_b, ybuf);
    k_final<<<1, 256, 0, stream>>>(ybuf, bn3_g, bn3_b, targets, out);
}

// Round 4
// 558.253 us; speedup vs baseline: 3.4778x; 1.1846x over previous
//
#include <hip/hip_runtime.h>
#include <hip/hip_bf16.h>

// TransMatch round 4: score volume as per-layer 3072x3072x512 fp16 GEMM
// (m97-style: global_load_lds staging, 128x128 tiles, 16x16x32 MFMA) with
// fused sigmoid+row/col-max epilogue via uint-key atomics. fc2 -> fp16 GEMM.
//
// ws layout (float words):
//   Qh   fp16 [2][8][3072][512]      = 12,582,912 f
//   xkey u32  [8][512][192]          =    786,432 f
//   xh   fp16 [8][512][192]          =    393,216 f
//   w2h  fp16 [8][2048][192]         =  1,572,864 f
//   hb   fp16 [8][512][2048]         =  4,194,304 f
//   bn2m/bn2r f32 [8][2048] x2, ybuf [8][512]
// total ~78.3 MB

#define EPS_ 1e-5f

typedef __attribute__((ext_vector_type(8))) _Float16 fp16x8;
typedef __attribute__((ext_vector_type(4)))  float   f32x4;
typedef __attribute__((ext_vector_type(16))) float   f32x16;

__device__ __forceinline__ unsigned fkey(float f) {
    unsigned u = __float_as_uint(f);
    return (u & 0x80000000u) ? ~u : (u | 0x80000000u);
}
__device__ __forceinline__ float funkey(unsigned k) {
    return (k & 0x80000000u) ? __uint_as_float(k & 0x7FFFFFFFu)
                             : __uint_as_float(~k);
}
__device__ __forceinline__ void gld16(const void* gp, void* lp) {
    __builtin_amdgcn_global_load_lds(
        (const __attribute__((address_space(1))) unsigned*)gp,
        (__attribute__((address_space(3))) unsigned*)lp, 16, 0, 0);
}

// ---------------- K1: fc0 via MFMA (unchanged from round 3) ----------------
__global__ __launch_bounds__(256) void k_fc0(const float* __restrict__ qfeat,
                                             const float* __restrict__ gfeat,
                                             const float* __restrict__ w0,
                                             const float* __restrict__ b0,
                                             _Float16* __restrict__ Qh) {
    int bid = blockIdx.x;
    int et = bid & 1;  bid >>= 1;
    int tt = bid % 3;  bid /= 3;
    int b  = bid & 15; bid >>= 4;
    int l  = bid & 7;  bid >>= 3;
    int sel = bid;
    const float* feat  = sel ? gfeat : qfeat;
    const float* Af = feat + (size_t)b * 4096 * 192 + (size_t)l * 512 * 192;
    const float* Wf = w0 + (size_t)l * 262144;
    int t0 = tt * 64, e0 = et * 256;

    __shared__ __align__(16) char At[64 * 80];
    __shared__ __align__(16) char Bt[256 * 80];

    int tid = threadIdx.x;
    int lane = tid & 63;
    int w = tid >> 6;
    int half = lane >> 5;
    int lrow = lane & 31;

    f32x16 acc[2][2];
    #pragma unroll
    for (int mi = 0; mi < 2; mi++)
        #pragma unroll
        for (int ni = 0; ni < 2; ni++)
            #pragma unroll
            for (int r = 0; r < 16; r++) acc[mi][ni][r] = 0.f;

    for (int d0 = 0; d0 < 512; d0 += 32) {
        __syncthreads();
        {
            int tA = tid & 63;
            int dA = tid >> 6;
            #pragma unroll
            for (int r = 0; r < 8; r++) {
                int d = dA + r * 4;
                float v = Af[(size_t)(d0 + d) * 192 + t0 + tA];
                *(_Float16*)(At + tA * 80 + d * 2) = (_Float16)v;
            }
        }
        {
            #pragma unroll
            for (int p = 0; p < 8; p++) {
                int s = tid + p * 256;
                int e = s >> 3;
                int q = s & 7;
                float4 wv = *(const float4*)(Wf + (size_t)(e0 + e) * 512 + d0 + q * 4);
                _Float16 h[4] = {(_Float16)wv.x, (_Float16)wv.y, (_Float16)wv.z, (_Float16)wv.w};
                *(uint2*)(Bt + e * 80 + q * 8) = *(uint2*)h;
            }
        }
        __syncthreads();
        #pragma unroll
        for (int ks = 0; ks < 2; ks++) {
            int koff = ks * 32 + half * 16;
            fp16x8 a[2], bf[2];
            #pragma unroll
            for (int mi = 0; mi < 2; mi++)
                a[mi] = *(const fp16x8*)(At + (mi * 32 + lrow) * 80 + koff);
            #pragma unroll
            for (int ni = 0; ni < 2; ni++)
                bf[ni] = *(const fp16x8*)(Bt + (w * 64 + ni * 32 + lrow) * 80 + koff);
            #pragma unroll
            for (int mi = 0; mi < 2; mi++)
                #pragma unroll
                for (int ni = 0; ni < 2; ni++)
                    acc[mi][ni] = __builtin_amdgcn_mfma_f32_32x32x16_f16(a[mi], bf[ni], acc[mi][ni], 0, 0, 0);
        }
    }

    _Float16* Obase = Qh + ((size_t)(sel * 8 + l) * 16 + b) * 98304;
    #pragma unroll
    for (int ni = 0; ni < 2; ni++) {
        int e = e0 + w * 64 + ni * 32 + lrow;
        float bias = b0[l * 512 + e];
        #pragma unroll
        for (int mi = 0; mi < 2; mi++) {
            #pragma unroll
            for (int r = 0; r < 16; r++) {
                int t = t0 + mi * 32 + (r & 3) + 8 * (r >> 2) + 4 * half;
                Obase[(size_t)t * 512 + e] = (_Float16)(acc[mi][ni][r] + bias);
            }
        }
    }
}

// ---------------- K1b: convert w2 fp32 -> fp16 ----------------
__global__ __launch_bounds__(256) void k_cvt(const float* __restrict__ src,
                                             _Float16* __restrict__ dst) {
    int i = blockIdx.x * 256 + threadIdx.x;   // 786432 threads x 4 elements
    float4 v = *(const float4*)(src + (size_t)i * 4);
    _Float16 h[4] = {(_Float16)v.x, (_Float16)v.y, (_Float16)v.z, (_Float16)v.w};
    *(uint2*)(dst + (size_t)i * 4) = *(uint2*)h;
}

// ---------------- K2: per-layer big GEMM + fused sigmoid/max ----------------
// C[gm, gn] = Query[gm,:] . Key[gn,:], gm = q*192+t, gn = k*192+s.
// 128x128 tile per block; 4 waves (2x2 of 64x64), 4x4 frags of 16x16x32.
__global__ __launch_bounds__(256) void k_score(const _Float16* __restrict__ Qh,
                                               const float* __restrict__ se,
                                               unsigned* __restrict__ xkey) {
    int bid = blockIdx.x;
    int l = bid / 576;
    int rem = bid - l * 576;
    int grp = rem / 96;            // 6 groups of 4 nt
    int within = rem - grp * 96;
    int mt = within >> 2;          // 24
    int nt = grp * 4 + (within & 3);
    int m0 = mt * 128, n0 = nt * 128;

    const char* Ag = (const char*)(Qh + (size_t)l * 1572864);         // query
    const char* Bg = (const char*)(Qh + (size_t)(8 + l) * 1572864);   // key
    const float* seb = se + (size_t)l * 36864;

    __shared__ __align__(16) char As[8192];   // [128 rows][64 B]
    __shared__ __align__(16) char Bs[8192];
    __shared__ unsigned rkey[2][128];         // [wn][row]  (max over s)
    __shared__ unsigned ckey[2][128];         // [wm][col]  (max over t)

    int tid = threadIdx.x;
    int lane = tid & 63;
    int w = tid >> 6;
    int wm = w >> 1, wn = w & 1;

    rkey[tid >> 7][tid & 127] = 0u;
    ckey[tid >> 7][tid & 127] = 0u;

    f32x4 acc[4][4];
    #pragma unroll
    for (int mi = 0; mi < 4; mi++)
        #pragma unroll
        for (int nj = 0; nj < 4; nj++)
            #pragma unroll
            for (int r = 0; r < 4; r++) acc[mi][nj][r] = 0.f;

    int srow = (lane >> 2);
    int sseg = (lane & 3) * 16;
    int c = lane & 15;
    int kq = (lane >> 4) * 16;

    for (int d0 = 0; d0 < 1024; d0 += 64) {   // byte offset within a 1024-B row
        __syncthreads();
        #pragma unroll
        for (int j = 0; j < 2; j++) {
            int r = w * 32 + j * 16 + srow;
            gld16(Ag + (size_t)(m0 + r) * 1024 + d0 + sseg, As + (w * 32 + j * 16) * 64);
            gld16(Bg + (size_t)(n0 + r) * 1024 + d0 + sseg, Bs + (w * 32 + j * 16) * 64);
        }
        __syncthreads();
        fp16x8 a[4], b[4];
        #pragma unroll
        for (int mi = 0; mi < 4; mi++)
            a[mi] = *(const fp16x8*)(As + (wm * 64 + mi * 16 + c) * 64 + kq);
        #pragma unroll
        for (int nj = 0; nj < 4; nj++)
            b[nj] = *(const fp16x8*)(Bs + (wn * 64 + nj * 16 + c) * 64 + kq);
        #pragma unroll
        for (int mi = 0; mi < 4; mi++)
            #pragma unroll
            for (int nj = 0; nj < 4; nj++)
                acc[mi][nj] = __builtin_amdgcn_mfma_f32_16x16x32_f16(a[mi], b[nj], acc[mi][nj], 0, 0, 0);
    }

    // ---- epilogue: v = C * sigmoid(se[s,t]); row-max over s, col-max over t ----
    int gmb = m0 + wm * 64;           // wave row base (64-aligned -> single q)
    int gnb = n0 + wn * 64;           // wave col base (single k)
    int tb = gmb % 192;               // t base
    int sb = gnb % 192;               // s base
    int rq = (lane >> 4) * 4;

    float rowp[4][4];                 // [mi][r] max over this lane's 4 cols
    float colp[4];                    // [nj]    max over this lane's 16 rows
    #pragma unroll
    for (int mi = 0; mi < 4; mi++)
        #pragma unroll
        for (int r = 0; r < 4; r++) rowp[mi][r] = -3.4e38f;
    #pragma unroll
    for (int nj = 0; nj < 4; nj++) colp[nj] = -3.4e38f;

    #pragma unroll
    for (int mi = 0; mi < 4; mi++) {
        #pragma unroll
        for (int nj = 0; nj < 4; nj++) {
            int s = sb + nj * 16 + c;
            #pragma unroll
            for (int r = 0; r < 4; r++) {
                int t = tb + mi * 16 + rq + r;
                float m = seb[(size_t)s * 192 + t];
                float v = acc[mi][nj][r] * (1.f / (1.f + __expf(-m)));
                rowp[mi][r] = fmaxf(rowp[mi][r], v);
                colp[nj] = fmaxf(colp[nj], v);
            }
        }
    }
    // col: reduce across row-quads (lanes xor 16,32)
    #pragma unroll
    for (int nj = 0; nj < 4; nj++) {
        colp[nj] = fmaxf(colp[nj], __shfl_xor(colp[nj], 16));
        colp[nj] = fmaxf(colp[nj], __shfl_xor(colp[nj], 32));
    }
    if (lane < 16) {
        #pragma unroll
        for (int nj = 0; nj < 4; nj++)
            atomicMax(&ckey[wm][wn * 64 + nj * 16 + lane], fkey(colp[nj]));
    }
    // row: reduce across the 16 col-lanes (xor 1,2,4,8)
    #pragma unroll
    for (int st = 1; st <= 8; st <<= 1)
        #pragma unroll
        for (int mi = 0; mi < 4; mi++)
            #pragma unroll
            for (int r = 0; r < 4; r++)
                rowp[mi][r] = fmaxf(rowp[mi][r], __shfl_xor(rowp[mi][r], st));
    if (c == 0) {
        #pragma unroll
        for (int mi = 0; mi < 4; mi++)
            #pragma unroll
            for (int r = 0; r < 4; r++)
                atomicMax(&rkey[wn][wm * 64 + mi * 16 + rq + r], fkey(rowp[mi][r]));
    }
    __syncthreads();

    // flush 512 LDS entries -> global xkey
    {
        int seg = tid >> 7, idx = tid & 127;
        // row entry: row idx, col segment seg
        int gm = m0 + idx;
        int q = gm / 192, t = gm - q * 192;
        int k = (n0 + seg * 64) / 192;
        atomicMax(&xkey[((size_t)l * 512 + 2 * (q * 16 + k)) * 192 + t], rkey[seg][idx]);
        // col entry: col idx, row segment seg
        int gn = n0 + idx;
        int k2 = gn / 192, s = gn - k2 * 192;
        int q2 = (m0 + seg * 64) / 192;
        atomicMax(&xkey[((size_t)l * 512 + 2 * (q2 * 16 + k2) + 1) * 192 + s], ckey[seg][idx]);
    }
}

// ---------------- K3: bn1 stats + decode + normalized fp16 x ----------------
__global__ __launch_bounds__(256) void k_bn1(const unsigned* __restrict__ xkey,
                                             const float* __restrict__ g1,
                                             const float* __restrict__ b1,
                                             _Float16* __restrict__ xh) {
    int l = blockIdx.x;
    const unsigned* xk = xkey + (size_t)l * 98304;
    int tid = threadIdx.x;
    float s = 0.f, s2 = 0.f;
    for (int i = tid; i < 98304; i += 256) {
        float v = funkey(xk[i]);
        s += v; s2 += v * v;
    }
    __shared__ float rs[4], rs2[4], stats[2];
    int lane = tid & 63, w = tid >> 6;
    #pragma unroll
    for (int o = 32; o; o >>= 1) { s += __shfl_down(s, o); s2 += __shfl_down(s2, o); }
    if (lane == 0) { rs[w] = s; rs2[w] = s2; }
    __syncthreads();
    if (tid == 0) {
        float S1 = rs[0] + rs[1] + rs[2] + rs[3];
        float S2 = rs2[0] + rs2[1] + rs2[2] + rs2[3];
        float mu = S1 * (1.f / 98304.f);
        float var = S2 * (1.f / 98304.f) - mu * mu;
        stats[0] = mu;
        stats[1] = rsqrtf(var + EPS_);
    }
    __syncthreads();
    float a1 = g1[l] * stats[1];
    float c1 = b1[l] - stats[0] * a1;
    _Float16* xo = xh + (size_t)l * 98304;
    for (int i = tid; i < 98304; i += 256)
        xo[i] = (_Float16)(funkey(xk[i]) * a1 + c1);
}

// ---------------- K4: fc2 as fp16 GEMM (M=512,N=2048,K=192) ----------------
__global__ __launch_bounds__(256) void k_fc2(const _Float16* __restrict__ xh,
                                             const _Float16* __restrict__ w2h,
                                             const float* __restrict__ b2,
                                             _Float16* __restrict__ hb) {
    int bid = blockIdx.x;
    int l = bid >> 6;
    int rem = bid & 63;
    int mt = rem & 3, nt = rem >> 2;
    int m0 = mt * 128, n0 = nt * 128;
    const char* Ag = (const char*)(xh + (size_t)l * 98304);     // rows 384 B
    const char* Bg = (const char*)(w2h + (size_t)l * 393216);

    __shared__ __align__(16) char As[8192];
    __shared__ __align__(16) char Bs[8192];

    int tid = threadIdx.x;
    int lane = tid & 63;
    int w = tid >> 6;
    int wm = w >> 1, wn = w & 1;

    f32x4 acc[4][4];
    #pragma unroll
    for (int mi = 0; mi < 4; mi++)
        #pragma unroll
        for (int nj = 0; nj < 4; nj++)
            #pragma unroll
            for (int r = 0; r < 4; r++) acc[mi][nj][r] = 0.f;

    int srow = (lane >> 2);
    int sseg = (lane & 3) * 16;
    int c = lane & 15;
    int kq = (lane >> 4) * 16;

    for (int d0 = 0; d0 < 384; d0 += 64) {
        __syncthreads();
        #pragma unroll
        for (int j = 0; j < 2; j++) {
            int r = w * 32 + j * 16 + srow;
            gld16(Ag + (size_t)(m0 + r) * 384 + d0 + sseg, As + (w * 32 + j * 16) * 64);
            gld16(Bg + (size_t)(n0 + r) * 384 + d0 + sseg, Bs + (w * 32 + j * 16) * 64);
        }
        __syncthreads();
        fp16x8 a[4], b[4];
        #pragma unroll
        for (int mi = 0; mi < 4; mi++)
            a[mi] = *(const fp16x8*)(As + (wm * 64 + mi * 16 + c) * 64 + kq);
        #pragma unroll
        for (int nj = 0; nj < 4; nj++)
            b[nj] = *(const fp16x8*)(Bs + (wn * 64 + nj * 16 + c) * 64 + kq);
        #pragma unroll
        for (int mi = 0; mi < 4; mi++)
            #pragma unroll
            for (int nj = 0; nj < 4; nj++)
                acc[mi][nj] = __builtin_amdgcn_mfma_f32_16x16x32_f16(a[mi], b[nj], acc[mi][nj], 0, 0, 0);
    }

    int rq = (lane >> 4) * 4;
    _Float16* ho = hb + (size_t)l * 1048576;
    #pragma unroll
    for (int nj = 0; nj < 4; nj++) {
        int gf = n0 + wn * 64 + nj * 16 + c;
        float bias = b2[l * 2048 + gf];
        #pragma unroll
        for (int mi = 0; mi < 4; mi++) {
            #pragma unroll
            for (int r = 0; r < 4; r++) {
                int gm = m0 + wm * 64 + mi * 16 + rq + r;
                ho[(size_t)gm * 2048 + gf] = (_Float16)(acc[mi][nj][r] + bias);
            }
        }
    }
}

// ---------------- K5: bn2 per-feature stats (fp16 h) ----------------
__global__ __launch_bounds__(256) void k_bn2stats(const _Float16* __restrict__ hb,
                                                  float* __restrict__ bn2m,
                                                  float* __restrict__ bn2r) {
    int f = (blockIdx.x & 7) * 256 + threadIdx.x;
    int l = blockIdx.x >> 3;
    const _Float16* h = hb + (size_t)l * 1048576 + f;
    float s = 0.f, s2 = 0.f;
    for (int n = 0; n < 512; n++) { float v = (float)h[(size_t)n * 2048]; s += v; s2 += v * v; }
    float mu = s * (1.f / 512.f);
    float var = s2 * (1.f / 512.f) - mu * mu;
    bn2m[l * 2048 + f] = mu;
    bn2r[l * 2048 + f] = rsqrtf(var + EPS_);
}

// ---------------- K6: bn2 + relu + fc3 dot ----------------
__global__ __launch_bounds__(256) void k_fc3(const _Float16* __restrict__ hb,
                                             const float* __restrict__ bn2m,
                                             const float* __restrict__ bn2r,
                                             const float* __restrict__ g2,
                                             const float* __restrict__ bb2,
                                             const float* __restrict__ w3,
                                             const float* __restrict__ b3,
                                             float* __restrict__ ybuf) {
    int n = blockIdx.x & 511;
    int l = blockIdx.x >> 9;
    const _Float16* h = hb + ((size_t)l * 512 + n) * 2048;
    int tid = threadIdx.x;
    float sum = 0.f;
    for (int f = tid; f < 2048; f += 256) {
        float a2 = g2[l * 2048 + f] * bn2r[l * 2048 + f];
        float c2 = bb2[l * 2048 + f] - bn2m[l * 2048 + f] * a2;
        float v = (float)h[f] * a2 + c2;
        v = fmaxf(v, 0.f);
        sum += v * w3[l * 2048 + f];
    }
    __shared__ float red[4];
    int lane = tid & 63, w = tid >> 6;
    #pragma unroll
    for (int o = 32; o; o >>= 1) sum += __shfl_down(sum, o);
    if (lane == 0) red[w] = sum;
    __syncthreads();
    if (tid == 0) ybuf[l * 512 + n] = red[0] + red[1] + red[2] + red[3] + b3[l];
}

// ---------------- K7: pair-sum + bn3 + layer-sum + pair_labels ----------------
__global__ __launch_bounds__(256) void k_final(const float* __restrict__ ybuf,
                                               const float* __restrict__ g3,
                                               const float* __restrict__ bb3,
                                               const int* __restrict__ targets,
                                               float* __restrict__ out) {
    int tid = threadIdx.x;
    __shared__ float red[8];
    float scoreacc = 0.f;
    for (int l = 0; l < 8; l++) {
        float z = ybuf[l * 512 + 2 * tid] + ybuf[l * 512 + 2 * tid + 1];
        float s = z, s2 = z * z;
        int lane = tid & 63, w = tid >> 6;
        #pragma unroll
        for (int o = 32; o; o >>= 1) { s += __shfl_down(s, o); s2 += __shfl_down(s2, o); }
        if (lane == 0) { red[w] = s; red[4 + w] = s2; }
        __syncthreads();
        float S1 = red[0] + red[1] + red[2] + red[3];
        float S2 = red[4] + red[5] + red[6] + red[7];
        float mu = S1 * (1.f / 256.f);
        float var = S2 * (1.f / 256.f) - mu * mu;
        float rstd = rsqrtf(var + EPS_);
        scoreacc += g3[l] * (z - mu) * rstd + bb3[l];
        __syncthreads();
    }
    out[tid] = scoreacc;
    int i = tid >> 4, j = tid & 15;
    out[256 + tid] = (targets[i] == targets[j]) ? 1.f : 0.f;
}

extern "C" void kernel_launch(void* const* d_in, const int* in_sizes, int n_in,
                              void* d_out, int out_size, void* d_ws, size_t ws_size,
                              hipStream_t stream) {
    const float* q_feat = (const float*)d_in[0];
    const float* g_feat = (const float*)d_in[1];
    const int*   targets = (const int*)d_in[2];
    const float* se     = (const float*)d_in[3];
    const float* fc0_w  = (const float*)d_in[4];
    const float* fc0_b  = (const float*)d_in[5];
    const float* bn1_g  = (const float*)d_in[6];
    const float* bn1_b  = (const float*)d_in[7];
    const float* fc2_w  = (const float*)d_in[8];
    const float* fc2_b  = (const float*)d_in[9];
    const float* bn2_g  = (const float*)d_in[10];
    const float* bn2_b  = (const float*)d_in[11];
    const float* fc3_w  = (const float*)d_in[12];
    const float* fc3_b  = (const float*)d_in[13];
    const float* bn3_g  = (const float*)d_in[14];
    const float* bn3_b  = (const float*)d_in[15];

    float* ws = (float*)d_ws;
    _Float16* Qh   = (_Float16*)ws;                      // 12,582,912 f
    unsigned* xkey = (unsigned*)(ws + 12582912);         //    786,432 f
    _Float16* xh   = (_Float16*)(ws + 13369344);         //    393,216 f
    _Float16* w2h  = (_Float16*)(ws + 13762560);         //  1,572,864 f
    _Float16* hb   = (_Float16*)(ws + 15335424);         //  4,194,304 f
    float* bn2m = ws + 19529728;
    float* bn2r = bn2m + 16384;
    float* ybuf = bn2r + 16384;
    float* out  = (float*)d_out;

    k_fc0<<<1536, 256, 0, stream>>>(q_feat, g_feat, fc0_w, fc0_b, Qh);
    k_cvt<<<3072, 256, 0, stream>>>(fc2_w, w2h);
    hipMemsetAsync(xkey, 0, 786432 * sizeof(unsigned), stream);
    k_score<<<4608, 256, 0, stream>>>(Qh, se, xkey);
    k_bn1<<<8, 256, 0, stream>>>(xkey, bn1_g, bn1_b, xh);
    k_fc2<<<512, 256, 0, stream>>>(xh, w2h, fc2_b, hb);
    k_bn2stats<<<64, 256, 0, stream>>>(hb, bn2m, bn2r);
    k_fc3<<<4096, 256, 0, stream>>>(hb, bn2m, bn2r, bn2_g, bn2_b, fc3_w, fc3_b, ybuf);
    k_final<<<1, 256, 0, stream>>>(ybuf, bn3_g, bn3_b, targets, out);
}

// Round 5
// 526.892 us; speedup vs baseline: 3.6848x; 1.0595x over previous
//
#include <hip/hip_runtime.h>
#include <hip/hip_bf16.h>

// TransMatch round 5:
//  - sig = sigmoid(se) precomputed once (reused 256x per element)
//  - k_score operands swapped (A=Key, B=Query) so epilogue sig loads are
//    lane-coalesced; per-wave single-writer LDS maxes (no LDS atomics)
//  - bn2 stats fused into fc2 epilogue (atomicAdd sum/sumsq); k_bn2stats gone
//  - fc0 LDS transpose writes packed to b32
//
// ws layout (float words):
//   Qh   fp16 [2][8][3072][512]  @ 0          = 12,582,912 f
//   sig  f32  [8][192][192]      @ 12,582,912 =    294,912 f
//   xkey u32  [8][512][192]      @ 12,877,824 =    786,432 f
//   xh   fp16 [8][512][192]      @ 13,664,256 =    393,216 f
//   w2h  fp16 [8][2048][192]     @ 14,057,472 =  1,572,864 f
//   hb   fp16 [8][512][2048]     @ 15,630,336 =  4,194,304 f
//   bn2sum f32 [8][2048]         @ 19,824,640 =     16,384 f
//   bn2sq  f32 [8][2048]         @ 19,841,024 =     16,384 f
//   ybuf f32 [8][512]            @ 19,857,408 =      4,096 f
// total ~79.5 MB

#define EPS_ 1e-5f

typedef __attribute__((ext_vector_type(8))) _Float16 fp16x8;
typedef __attribute__((ext_vector_type(4)))  float   f32x4;
typedef __attribute__((ext_vector_type(16))) float   f32x16;

__device__ __forceinline__ unsigned fkey(float f) {
    unsigned u = __float_as_uint(f);
    return (u & 0x80000000u) ? ~u : (u | 0x80000000u);
}
__device__ __forceinline__ float funkey(unsigned k) {
    return (k & 0x80000000u) ? __uint_as_float(k & 0x7FFFFFFFu)
                             : __uint_as_float(~k);
}
__device__ __forceinline__ void gld16(const void* gp, void* lp) {
    __builtin_amdgcn_global_load_lds(
        (const __attribute__((address_space(1))) unsigned*)gp,
        (__attribute__((address_space(3))) unsigned*)lp, 16, 0, 0);
}

// ---------------- K0: sig = sigmoid(se) ----------------
__global__ __launch_bounds__(256) void k_sig(const float* __restrict__ se,
                                             float* __restrict__ sig) {
    int i = blockIdx.x * 256 + threadIdx.x;   // 73728 x float4
    float4 v = *(const float4*)(se + (size_t)i * 4);
    float4 o;
    o.x = 1.f / (1.f + __expf(-v.x));
    o.y = 1.f / (1.f + __expf(-v.y));
    o.z = 1.f / (1.f + __expf(-v.z));
    o.w = 1.f / (1.f + __expf(-v.w));
    *(float4*)(sig + (size_t)i * 4) = o;
}

// ---------------- K1: fc0 via MFMA ----------------
__global__ __launch_bounds__(256) void k_fc0(const float* __restrict__ qfeat,
                                             const float* __restrict__ gfeat,
                                             const float* __restrict__ w0,
                                             const float* __restrict__ b0,
                                             _Float16* __restrict__ Qh) {
    int bid = blockIdx.x;
    int et = bid & 1;  bid >>= 1;
    int tt = bid % 3;  bid /= 3;
    int b  = bid & 15; bid >>= 4;
    int l  = bid & 7;  bid >>= 3;
    int sel = bid;
    const float* feat  = sel ? gfeat : qfeat;
    const float* Af = feat + (size_t)b * 4096 * 192 + (size_t)l * 512 * 192;
    const float* Wf = w0 + (size_t)l * 262144;
    int t0 = tt * 64, e0 = et * 256;

    __shared__ __align__(16) char At[64 * 80];
    __shared__ __align__(16) char Bt[256 * 80];

    int tid = threadIdx.x;
    int lane = tid & 63;
    int w = tid >> 6;
    int half = lane >> 5;
    int lrow = lane & 31;

    f32x16 acc[2][2];
    #pragma unroll
    for (int mi = 0; mi < 2; mi++)
        #pragma unroll
        for (int ni = 0; ni < 2; ni++)
            #pragma unroll
            for (int r = 0; r < 16; r++) acc[mi][ni][r] = 0.f;

    for (int d0 = 0; d0 < 512; d0 += 32) {
        __syncthreads();
        {   // A transpose: packed b32 writes (2 halfs)
            int tA = tid & 63;
            int dp = tid >> 6;       // 0..3
            #pragma unroll
            for (int r = 0; r < 4; r++) {
                int d = dp * 2 + r * 8;
                float v0 = Af[(size_t)(d0 + d) * 192 + t0 + tA];
                float v1 = Af[(size_t)(d0 + d + 1) * 192 + t0 + tA];
                _Float16 h2[2] = {(_Float16)v0, (_Float16)v1};
                *(unsigned*)(At + tA * 80 + d * 2) = *(unsigned*)h2;
            }
        }
        {
            #pragma unroll
            for (int p = 0; p < 8; p++) {
                int s = tid + p * 256;
                int e = s >> 3;
                int q = s & 7;
                float4 wv = *(const float4*)(Wf + (size_t)(e0 + e) * 512 + d0 + q * 4);
                _Float16 h[4] = {(_Float16)wv.x, (_Float16)wv.y, (_Float16)wv.z, (_Float16)wv.w};
                *(uint2*)(Bt + e * 80 + q * 8) = *(uint2*)h;
            }
        }
        __syncthreads();
        #pragma unroll
        for (int ks = 0; ks < 2; ks++) {
            int koff = ks * 32 + half * 16;
            fp16x8 a[2], bf[2];
            #pragma unroll
            for (int mi = 0; mi < 2; mi++)
                a[mi] = *(const fp16x8*)(At + (mi * 32 + lrow) * 80 + koff);
            #pragma unroll
            for (int ni = 0; ni < 2; ni++)
                bf[ni] = *(const fp16x8*)(Bt + (w * 64 + ni * 32 + lrow) * 80 + koff);
            #pragma unroll
            for (int mi = 0; mi < 2; mi++)
                #pragma unroll
                for (int ni = 0; ni < 2; ni++)
                    acc[mi][ni] = __builtin_amdgcn_mfma_f32_32x32x16_f16(a[mi], bf[ni], acc[mi][ni], 0, 0, 0);
        }
    }

    _Float16* Obase = Qh + ((size_t)(sel * 8 + l) * 16 + b) * 98304;
    #pragma unroll
    for (int ni = 0; ni < 2; ni++) {
        int e = e0 + w * 64 + ni * 32 + lrow;
        float bias = b0[l * 512 + e];
        #pragma unroll
        for (int mi = 0; mi < 2; mi++) {
            #pragma unroll
            for (int r = 0; r < 16; r++) {
                int t = t0 + mi * 32 + (r & 3) + 8 * (r >> 2) + 4 * half;
                Obase[(size_t)t * 512 + e] = (_Float16)(acc[mi][ni][r] + bias);
            }
        }
    }
}

// ---------------- K1b: convert w2 fp32 -> fp16 ----------------
__global__ __launch_bounds__(256) void k_cvt(const float* __restrict__ src,
                                             _Float16* __restrict__ dst) {
    int i = blockIdx.x * 256 + threadIdx.x;
    float4 v = *(const float4*)(src + (size_t)i * 4);
    _Float16 h[4] = {(_Float16)v.x, (_Float16)v.y, (_Float16)v.z, (_Float16)v.w};
    *(uint2*)(dst + (size_t)i * 4) = *(uint2*)h;
}

// ---------------- K2: score GEMM (A=Key, B=Query) + fused sig/max ----------
// C[gm, gn] = Key[gm,:] . Query[gn,:], gm = k*192+s, gn = q*192+t.
// 128x128 tile; 4 waves 2x2 of 64x64; 4x4 frags of 16x16x32.
// C/D: col(lane&15) = t (contig in sig), row(quad*4+r) = s.
__global__ __launch_bounds__(256) void k_score(const _Float16* __restrict__ Qh,
                                               const float* __restrict__ sig,
                                               unsigned* __restrict__ xkey) {
    int bid = blockIdx.x;
    int l = bid / 576;
    int rem = bid - l * 576;
    int grp = rem / 96;
    int within = rem - grp * 96;
    int mt = within >> 2;
    int nt = grp * 4 + (within & 3);
    int m0 = mt * 128, n0 = nt * 128;

    const char* Ag = (const char*)(Qh + (size_t)(8 + l) * 1572864);   // key
    const char* Bg = (const char*)(Qh + (size_t)l * 1572864);         // query
    const float* sg = sig + (size_t)l * 36864;

    __shared__ __align__(16) char As[8192];   // [128 rows][64 B]
    __shared__ __align__(16) char Bs[8192];
    __shared__ unsigned tmaxL[4][64];         // [wm*2+wn][t-off]  (max over s)
    __shared__ unsigned smaxL[4][64];         // [wm*2+wn][s-off]  (max over t)

    int tid = threadIdx.x;
    int lane = tid & 63;
    int w = tid >> 6;
    int wm = w >> 1, wn = w & 1;

    f32x4 acc[4][4];
    #pragma unroll
    for (int mi = 0; mi < 4; mi++)
        #pragma unroll
        for (int nj = 0; nj < 4; nj++)
            #pragma unroll
            for (int r = 0; r < 4; r++) acc[mi][nj][r] = 0.f;

    int srow = (lane >> 2);
    int sseg = (lane & 3) * 16;
    int c = lane & 15;
    int kq = (lane >> 4) * 16;

    for (int d0 = 0; d0 < 1024; d0 += 64) {
        __syncthreads();
        #pragma unroll
        for (int j = 0; j < 2; j++) {
            int r = w * 32 + j * 16 + srow;
            gld16(Ag + (size_t)(m0 + r) * 1024 + d0 + sseg, As + (w * 32 + j * 16) * 64);
            gld16(Bg + (size_t)(n0 + r) * 1024 + d0 + sseg, Bs + (w * 32 + j * 16) * 64);
        }
        __syncthreads();
        fp16x8 a[4], b[4];
        #pragma unroll
        for (int mi = 0; mi < 4; mi++)
            a[mi] = *(const fp16x8*)(As + (wm * 64 + mi * 16 + c) * 64 + kq);
        #pragma unroll
        for (int nj = 0; nj < 4; nj++)
            b[nj] = *(const fp16x8*)(Bs + (wn * 64 + nj * 16 + c) * 64 + kq);
        #pragma unroll
        for (int mi = 0; mi < 4; mi++)
            #pragma unroll
            for (int nj = 0; nj < 4; nj++)
                acc[mi][nj] = __builtin_amdgcn_mfma_f32_16x16x32_f16(a[mi], b[nj], acc[mi][nj], 0, 0, 0);
    }

    // ---- epilogue ----
    int gmb = m0 + wm * 64;            // key rows: one k per wave (64 | 192)
    int kk = gmb / 192, sb = gmb - kk * 192;
    int gnb = n0 + wn * 64;            // query cols: one q per wave
    int qq = gnb / 192, tb = gnb - qq * 192;
    int rq = (lane >> 4) * 4;

    float rowm[4][4];                  // [mi][r]: per-s max over this lane's t
    float colm[4];                     // [nj]: per-t max over this lane's s
    #pragma unroll
    for (int mi = 0; mi < 4; mi++)
        #pragma unroll
        for (int r = 0; r < 4; r++) rowm[mi][r] = -3.4e38f;
    #pragma unroll
    for (int nj = 0; nj < 4; nj++) colm[nj] = -3.4e38f;

    #pragma unroll
    for (int mi = 0; mi < 4; mi++) {
        #pragma unroll
        for (int r = 0; r < 4; r++) {
            int s = sb + mi * 16 + rq + r;
            const float* srow_p = sg + (size_t)s * 192 + tb;
            #pragma unroll
            for (int nj = 0; nj < 4; nj++) {
                float m = srow_p[nj * 16 + c];          // lane-coalesced
                float v = acc[mi][nj][r] * m;
                rowm[mi][r] = fmaxf(rowm[mi][r], v);
                colm[nj] = fmaxf(colm[nj], v);
            }
        }
    }
    // per-t max: reduce across quads (s direction)
    #pragma unroll
    for (int nj = 0; nj < 4; nj++) {
        colm[nj] = fmaxf(colm[nj], __shfl_xor(colm[nj], 16));
        colm[nj] = fmaxf(colm[nj], __shfl_xor(colm[nj], 32));
    }
    if (lane < 16) {
        #pragma unroll
        for (int nj = 0; nj < 4; nj++)
            tmaxL[wm * 2 + wn][nj * 16 + lane] = fkey(colm[nj]);
    }
    // per-s max: reduce across the 16 t-lanes
    #pragma unroll
    for (int st = 1; st <= 8; st <<= 1)
        #pragma unroll
        for (int mi = 0; mi < 4; mi++)
            #pragma unroll
            for (int r = 0; r < 4; r++)
                rowm[mi][r] = fmaxf(rowm[mi][r], __shfl_xor(rowm[mi][r], st));
    if (c == 0) {
        #pragma unroll
        for (int mi = 0; mi < 4; mi++)
            #pragma unroll
            for (int r = 0; r < 4; r++)
                smaxL[wm * 2 + wn][mi * 16 + rq + r] = fkey(rowm[mi][r]);
    }
    __syncthreads();

    // flush 512 entries -> global
    #pragma unroll
    for (int rep = 0; rep < 2; rep++) {
        int idx = tid + rep * 256;         // 0..511
        int wp = idx >> 7;                 // wm*2+wn
        int which = (idx >> 6) & 1;        // 0=tmax, 1=smax
        int off = idx & 63;
        int wmf = wp >> 1, wnf = wp & 1;
        int kf = (m0 + wmf * 64) / 192, sbf = (m0 + wmf * 64) % 192;
        int qf = (n0 + wnf * 64) / 192, tbf = (n0 + wnf * 64) % 192;
        int jp = qf * 16 + kf;
        if (which == 0)
            atomicMax(&xkey[((size_t)l * 512 + 2 * jp) * 192 + tbf + off], tmaxL[wp][off]);
        else
            atomicMax(&xkey[((size_t)l * 512 + 2 * jp + 1) * 192 + sbf + off], smaxL[wp][off]);
    }
}

// ---------------- K3: bn1 stats + decode + normalized fp16 x ----------------
__global__ __launch_bounds__(256) void k_bn1(const unsigned* __restrict__ xkey,
                                             const float* __restrict__ g1,
                                             const float* __restrict__ b1,
                                             _Float16* __restrict__ xh) {
    int l = blockIdx.x;
    const unsigned* xk = xkey + (size_t)l * 98304;
    int tid = threadIdx.x;
    float s = 0.f, s2 = 0.f;
    for (int i = tid; i < 98304; i += 256) {
        float v = funkey(xk[i]);
        s += v; s2 += v * v;
    }
    __shared__ float rs[4], rs2[4], stats[2];
    int lane = tid & 63, w = tid >> 6;
    #pragma unroll
    for (int o = 32; o; o >>= 1) { s += __shfl_down(s, o); s2 += __shfl_down(s2, o); }
    if (lane == 0) { rs[w] = s; rs2[w] = s2; }
    __syncthreads();
    if (tid == 0) {
        float S1 = rs[0] + rs[1] + rs[2] + rs[3];
        float S2 = rs2[0] + rs2[1] + rs2[2] + rs2[3];
        float mu = S1 * (1.f / 98304.f);
        float var = S2 * (1.f / 98304.f) - mu * mu;
        stats[0] = mu;
        stats[1] = rsqrtf(var + EPS_);
    }
    __syncthreads();
    float a1 = g1[l] * stats[1];
    float c1 = b1[l] - stats[0] * a1;
    _Float16* xo = xh + (size_t)l * 98304;
    for (int i = tid; i < 98304; i += 256)
        xo[i] = (_Float16)(funkey(xk[i]) * a1 + c1);
}

// ---------------- K4: fc2 fp16 GEMM + fused bn2 partial stats ----------------
__global__ __launch_bounds__(256) void k_fc2(const _Float16* __restrict__ xh,
                                             const _Float16* __restrict__ w2h,
                                             const float* __restrict__ b2,
                                             _Float16* __restrict__ hb,
                                             float* __restrict__ bn2sum,
                                             float* __restrict__ bn2sq) {
    int bid = blockIdx.x;
    int l = bid >> 6;
    int rem = bid & 63;
    int mt = rem & 3, nt = rem >> 2;
    int m0 = mt * 128, n0 = nt * 128;
    const char* Ag = (const char*)(xh + (size_t)l * 98304);
    const char* Bg = (const char*)(w2h + (size_t)l * 393216);

    __shared__ __align__(16) char As[8192];
    __shared__ __align__(16) char Bs[8192];

    int tid = threadIdx.x;
    int lane = tid & 63;
    int w = tid >> 6;
    int wm = w >> 1, wn = w & 1;

    f32x4 acc[4][4];
    #pragma unroll
    for (int mi = 0; mi < 4; mi++)
        #pragma unroll
        for (int nj = 0; nj < 4; nj++)
            #pragma unroll
            for (int r = 0; r < 4; r++) acc[mi][nj][r] = 0.f;

    int srow = (lane >> 2);
    int sseg = (lane & 3) * 16;
    int c = lane & 15;
    int kq = (lane >> 4) * 16;

    for (int d0 = 0; d0 < 384; d0 += 64) {
        __syncthreads();
        #pragma unroll
        for (int j = 0; j < 2; j++) {
            int r = w * 32 + j * 16 + srow;
            gld16(Ag + (size_t)(m0 + r) * 384 + d0 + sseg, As + (w * 32 + j * 16) * 64);
            gld16(Bg + (size_t)(n0 + r) * 384 + d0 + sseg, Bs + (w * 32 + j * 16) * 64);
        }
        __syncthreads();
        fp16x8 a[4], b[4];
        #pragma unroll
        for (int mi = 0; mi < 4; mi++)
            a[mi] = *(const fp16x8*)(As + (wm * 64 + mi * 16 + c) * 64 + kq);
        #pragma unroll
        for (int nj = 0; nj < 4; nj++)
            b[nj] = *(const fp16x8*)(Bs + (wn * 64 + nj * 16 + c) * 64 + kq);
        #pragma unroll
        for (int mi = 0; mi < 4; mi++)
            #pragma unroll
            for (int nj = 0; nj < 4; nj++)
                acc[mi][nj] = __builtin_amdgcn_mfma_f32_16x16x32_f16(a[mi], b[nj], acc[mi][nj], 0, 0, 0);
    }

    int rq = (lane >> 4) * 4;
    _Float16* ho = hb + (size_t)l * 1048576;
    float colsum[4], colsq[4];
    #pragma unroll
    for (int nj = 0; nj < 4; nj++) { colsum[nj] = 0.f; colsq[nj] = 0.f; }
    #pragma unroll
    for (int nj = 0; nj < 4; nj++) {
        int gf = n0 + wn * 64 + nj * 16 + c;
        float bias = b2[l * 2048 + gf];
        #pragma unroll
        for (int mi = 0; mi < 4; mi++) {
            #pragma unroll
            for (int r = 0; r < 4; r++) {
                int gm = m0 + wm * 64 + mi * 16 + rq + r;
                float v = acc[mi][nj][r] + bias;
                ho[(size_t)gm * 2048 + gf] = (_Float16)v;
                colsum[nj] += v;
                colsq[nj] += v * v;
            }
        }
    }
    #pragma unroll
    for (int nj = 0; nj < 4; nj++) {
        colsum[nj] += __shfl_xor(colsum[nj], 16);
        colsum[nj] += __shfl_xor(colsum[nj], 32);
        colsq[nj]  += __shfl_xor(colsq[nj], 16);
        colsq[nj]  += __shfl_xor(colsq[nj], 32);
    }
    if (lane < 16) {
        #pragma unroll
        for (int nj = 0; nj < 4; nj++) {
            int gf = n0 + wn * 64 + nj * 16 + lane;
            atomicAdd(&bn2sum[l * 2048 + gf], colsum[nj]);
            atomicAdd(&bn2sq[l * 2048 + gf], colsq[nj]);
        }
    }
}

// ---------------- K6: bn2(inline stats) + relu + fc3 dot ----------------
__global__ __launch_bounds__(256) void k_fc3(const _Float16* __restrict__ hb,
                                             const float* __restrict__ bn2sum,
                                             const float* __restrict__ bn2sq,
                                             const float* __restrict__ g2,
                                             const float* __restrict__ bb2,
                                             const float* __restrict__ w3,
                                             const float* __restrict__ b3,
                                             float* __restrict__ ybuf) {
    int n = blockIdx.x & 511;
    int l = blockIdx.x >> 9;
    const _Float16* h = hb + ((size_t)l * 512 + n) * 2048;
    int tid = threadIdx.x;
    float sum = 0.f;
    for (int f = tid; f < 2048; f += 256) {
        float mu = bn2sum[l * 2048 + f] * (1.f / 512.f);
        float var = bn2sq[l * 2048 + f] * (1.f / 512.f) - mu * mu;
        float a2 = g2[l * 2048 + f] * rsqrtf(var + EPS_);
        float c2 = bb2[l * 2048 + f] - mu * a2;
        float v = (float)h[f] * a2 + c2;
        v = fmaxf(v, 0.f);
        sum += v * w3[l * 2048 + f];
    }
    __shared__ float red[4];
    int lane = tid & 63, w = tid >> 6;
    #pragma unroll
    for (int o = 32; o; o >>= 1) sum += __shfl_down(sum, o);
    if (lane == 0) red[w] = sum;
    __syncthreads();
    if (tid == 0) ybuf[l * 512 + n] = red[0] + red[1] + red[2] + red[3] + b3[l];
}

// ---------------- K7: pair-sum + bn3 + layer-sum + pair_labels ----------------
__global__ __launch_bounds__(256) void k_final(const float* __restrict__ ybuf,
                                               const float* __restrict__ g3,
                                               const float* __restrict__ bb3,
                                               const int* __restrict__ targets,
                                               float* __restrict__ out) {
    int tid = threadIdx.x;
    __shared__ float red[8];
    float scoreacc = 0.f;
    for (int l = 0; l < 8; l++) {
        float z = ybuf[l * 512 + 2 * tid] + ybuf[l * 512 + 2 * tid + 1];
        float s = z, s2 = z * z;
        int lane = tid & 63, w = tid >> 6;
        #pragma unroll
        for (int o = 32; o; o >>= 1) { s += __shfl_down(s, o); s2 += __shfl_down(s2, o); }
        if (lane == 0) { red[w] = s; red[4 + w] = s2; }
        __syncthreads();
        float S1 = red[0] + red[1] + red[2] + red[3];
        float S2 = red[4] + red[5] + red[6] + red[7];
        float mu = S1 * (1.f / 256.f);
        float var = S2 * (1.f / 256.f) - mu * mu;
        float rstd = rsqrtf(var + EPS_);
        scoreacc += g3[l] * (z - mu) * rstd + bb3[l];
        __syncthreads();
    }
    out[tid] = scoreacc;
    int i = tid >> 4, j = tid & 15;
    out[256 + tid] = (targets[i] == targets[j]) ? 1.f : 0.f;
}

extern "C" void kernel_launch(void* const* d_in, const int* in_sizes, int n_in,
                              void* d_out, int out_size, void* d_ws, size_t ws_size,
                              hipStream_t stream) {
    const float* q_feat = (const float*)d_in[0];
    const float* g_feat = (const float*)d_in[1];
    const int*   targets = (const int*)d_in[2];
    const float* se     = (const float*)d_in[3];
    const float* fc0_w  = (const float*)d_in[4];
    const float* fc0_b  = (const float*)d_in[5];
    const float* bn1_g  = (const float*)d_in[6];
    const float* bn1_b  = (const float*)d_in[7];
    const float* fc2_w  = (const float*)d_in[8];
    const float* fc2_b  = (const float*)d_in[9];
    const float* bn2_g  = (const float*)d_in[10];
    const float* bn2_b  = (const float*)d_in[11];
    const float* fc3_w  = (const float*)d_in[12];
    const float* fc3_b  = (const float*)d_in[13];
    const float* bn3_g  = (const float*)d_in[14];
    const float* bn3_b  = (const float*)d_in[15];

    float* ws = (float*)d_ws;
    _Float16* Qh   = (_Float16*)ws;                      // 12,582,912 f
    float*    sig  = ws + 12582912;                      //    294,912 f
    unsigned* xkey = (unsigned*)(ws + 12877824);         //    786,432 f
    _Float16* xh   = (_Float16*)(ws + 13664256);         //    393,216 f
    _Float16* w2h  = (_Float16*)(ws + 14057472);         //  1,572,864 f
    _Float16* hb   = (_Float16*)(ws + 15630336);         //  4,194,304 f
    float* bn2sum = ws + 19824640;
    float* bn2sq  = ws + 19841024;
    float* ybuf   = ws + 19857408;
    float* out  = (float*)d_out;

    hipMemsetAsync(xkey, 0, 786432 * sizeof(unsigned), stream);
    hipMemsetAsync(bn2sum, 0, 2 * 16384 * sizeof(float), stream);
    k_sig<<<288, 256, 0, stream>>>(se, sig);
    k_cvt<<<3072, 256, 0, stream>>>(fc2_w, w2h);
    k_fc0<<<1536, 256, 0, stream>>>(q_feat, g_feat, fc0_w, fc0_b, Qh);
    k_score<<<4608, 256, 0, stream>>>(Qh, sig, xkey);
    k_bn1<<<8, 256, 0, stream>>>(xkey, bn1_g, bn1_b, xh);
    k_fc2<<<512, 256, 0, stream>>>(xh, w2h, fc2_b, hb, bn2sum, bn2sq);
    k_fc3<<<4096, 256, 0, stream>>>(hb, bn2sum, bn2sq, bn2_g, bn2_b, fc3_w, fc3_b, ybuf);
    k_final<<<1, 256, 0, stream>>>(ybuf, bn3_g, bn3_b, targets, out);
}

// Round 6
// 428.659 us; speedup vs baseline: 4.5292x; 1.2292x over previous
//
#include <hip/hip_runtime.h>
#include <hip/hip_bf16.h>

// TransMatch round 6:
//  - XOR bank swizzle (chunk q of row r at phys chunk q^((r>>1)&3)) in the
//    k_score / k_fc2 LDS tiles: fragment ds_read_b128 now bank-balanced.
//  - bn1 parallelized: 384-block partial stats + 768-block normalize.
//  - k_fc3 h-load vectorized (fp16x8).
//
// ws layout (float words):
//   Qh   fp16 [2][8][3072][512]  @ 0          = 12,582,912 f
//   sig  f32  [8][192][192]      @ 12,582,912 =    294,912 f
//   xkey u32  [8][512][192]      @ 12,877,824 =    786,432 f
//   xh   fp16 [8][512][192]      @ 13,664,256 =    393,216 f
//   w2h  fp16 [8][2048][192]     @ 14,057,472 =  1,572,864 f
//   hb   fp16 [8][512][2048]     @ 15,630,336 =  4,194,304 f
//   bn2sum f32 [8][2048]         @ 19,824,640 =     16,384 f
//   bn2sq  f32 [8][2048]         @ 19,841,024 =     16,384 f
//   bn1acc f32 [8][2]            @ 19,857,408 =         16 f
//   ybuf f32 [8][512]            @ 19,857,424 =      4,096 f

#define EPS_ 1e-5f

typedef __attribute__((ext_vector_type(8))) _Float16 fp16x8;
typedef __attribute__((ext_vector_type(4)))  float   f32x4;
typedef __attribute__((ext_vector_type(16))) float   f32x16;

__device__ __forceinline__ unsigned fkey(float f) {
    unsigned u = __float_as_uint(f);
    return (u & 0x80000000u) ? ~u : (u | 0x80000000u);
}
__device__ __forceinline__ float funkey(unsigned k) {
    return (k & 0x80000000u) ? __uint_as_float(k & 0x7FFFFFFFu)
                             : __uint_as_float(~k);
}
__device__ __forceinline__ void gld16(const void* gp, void* lp) {
    __builtin_amdgcn_global_load_lds(
        (const __attribute__((address_space(1))) unsigned*)gp,
        (__attribute__((address_space(3))) unsigned*)lp, 16, 0, 0);
}

// ---------------- K0: sig = sigmoid(se) ----------------
__global__ __launch_bounds__(256) void k_sig(const float* __restrict__ se,
                                             float* __restrict__ sig) {
    int i = blockIdx.x * 256 + threadIdx.x;
    float4 v = *(const float4*)(se + (size_t)i * 4);
    float4 o;
    o.x = 1.f / (1.f + __expf(-v.x));
    o.y = 1.f / (1.f + __expf(-v.y));
    o.z = 1.f / (1.f + __expf(-v.z));
    o.w = 1.f / (1.f + __expf(-v.w));
    *(float4*)(sig + (size_t)i * 4) = o;
}

// ---------------- K1: fc0 via MFMA ----------------
__global__ __launch_bounds__(256) void k_fc0(const float* __restrict__ qfeat,
                                             const float* __restrict__ gfeat,
                                             const float* __restrict__ w0,
                                             const float* __restrict__ b0,
                                             _Float16* __restrict__ Qh) {
    int bid = blockIdx.x;
    int et = bid & 1;  bid >>= 1;
    int tt = bid % 3;  bid /= 3;
    int b  = bid & 15; bid >>= 4;
    int l  = bid & 7;  bid >>= 3;
    int sel = bid;
    const float* feat  = sel ? gfeat : qfeat;
    const float* Af = feat + (size_t)b * 4096 * 192 + (size_t)l * 512 * 192;
    const float* Wf = w0 + (size_t)l * 262144;
    int t0 = tt * 64, e0 = et * 256;

    __shared__ __align__(16) char At[64 * 80];
    __shared__ __align__(16) char Bt[256 * 80];

    int tid = threadIdx.x;
    int lane = tid & 63;
    int w = tid >> 6;
    int half = lane >> 5;
    int lrow = lane & 31;

    f32x16 acc[2][2];
    #pragma unroll
    for (int mi = 0; mi < 2; mi++)
        #pragma unroll
        for (int ni = 0; ni < 2; ni++)
            #pragma unroll
            for (int r = 0; r < 16; r++) acc[mi][ni][r] = 0.f;

    for (int d0 = 0; d0 < 512; d0 += 32) {
        __syncthreads();
        {   // A transpose: packed b32 writes (2 halfs)
            int tA = tid & 63;
            int dp = tid >> 6;
            #pragma unroll
            for (int r = 0; r < 4; r++) {
                int d = dp * 2 + r * 8;
                float v0 = Af[(size_t)(d0 + d) * 192 + t0 + tA];
                float v1 = Af[(size_t)(d0 + d + 1) * 192 + t0 + tA];
                _Float16 h2[2] = {(_Float16)v0, (_Float16)v1};
                *(unsigned*)(At + tA * 80 + d * 2) = *(unsigned*)h2;
            }
        }
        {
            #pragma unroll
            for (int p = 0; p < 8; p++) {
                int s = tid + p * 256;
                int e = s >> 3;
                int q = s & 7;
                float4 wv = *(const float4*)(Wf + (size_t)(e0 + e) * 512 + d0 + q * 4);
                _Float16 h[4] = {(_Float16)wv.x, (_Float16)wv.y, (_Float16)wv.z, (_Float16)wv.w};
                *(uint2*)(Bt + e * 80 + q * 8) = *(uint2*)h;
            }
        }
        __syncthreads();
        #pragma unroll
        for (int ks = 0; ks < 2; ks++) {
            int koff = ks * 32 + half * 16;
            fp16x8 a[2], bf[2];
            #pragma unroll
            for (int mi = 0; mi < 2; mi++)
                a[mi] = *(const fp16x8*)(At + (mi * 32 + lrow) * 80 + koff);
            #pragma unroll
            for (int ni = 0; ni < 2; ni++)
                bf[ni] = *(const fp16x8*)(Bt + (w * 64 + ni * 32 + lrow) * 80 + koff);
            #pragma unroll
            for (int mi = 0; mi < 2; mi++)
                #pragma unroll
                for (int ni = 0; ni < 2; ni++)
                    acc[mi][ni] = __builtin_amdgcn_mfma_f32_32x32x16_f16(a[mi], bf[ni], acc[mi][ni], 0, 0, 0);
        }
    }

    _Float16* Obase = Qh + ((size_t)(sel * 8 + l) * 16 + b) * 98304;
    #pragma unroll
    for (int ni = 0; ni < 2; ni++) {
        int e = e0 + w * 64 + ni * 32 + lrow;
        float bias = b0[l * 512 + e];
        #pragma unroll
        for (int mi = 0; mi < 2; mi++) {
            #pragma unroll
            for (int r = 0; r < 16; r++) {
                int t = t0 + mi * 32 + (r & 3) + 8 * (r >> 2) + 4 * half;
                Obase[(size_t)t * 512 + e] = (_Float16)(acc[mi][ni][r] + bias);
            }
        }
    }
}

// ---------------- K1b: convert w2 fp32 -> fp16 ----------------
__global__ __launch_bounds__(256) void k_cvt(const float* __restrict__ src,
                                             _Float16* __restrict__ dst) {
    int i = blockIdx.x * 256 + threadIdx.x;
    float4 v = *(const float4*)(src + (size_t)i * 4);
    _Float16 h[4] = {(_Float16)v.x, (_Float16)v.y, (_Float16)v.z, (_Float16)v.w};
    *(uint2*)(dst + (size_t)i * 4) = *(uint2*)h;
}

// ---------------- K2: score GEMM (A=Key, B=Query) + fused sig/max ----------
// LDS tile rows are 64 B = 4 chunks of 16 B; chunk q of row r is stored at
// physical chunk q ^ ((r>>1)&3)  -> fragment b128 reads are bank-balanced.
__global__ __launch_bounds__(256) void k_score(const _Float16* __restrict__ Qh,
                                               const float* __restrict__ sig,
                                               unsigned* __restrict__ xkey) {
    int bid = blockIdx.x;
    int l = bid / 576;
    int rem = bid - l * 576;
    int grp = rem / 96;
    int within = rem - grp * 96;
    int mt = within >> 2;
    int nt = grp * 4 + (within & 3);
    int m0 = mt * 128, n0 = nt * 128;

    const char* Ag = (const char*)(Qh + (size_t)(8 + l) * 1572864);   // key
    const char* Bg = (const char*)(Qh + (size_t)l * 1572864);         // query
    const float* sg = sig + (size_t)l * 36864;

    __shared__ __align__(16) char As[8192];
    __shared__ __align__(16) char Bs[8192];
    __shared__ unsigned tmaxL[4][64];
    __shared__ unsigned smaxL[4][64];

    int tid = threadIdx.x;
    int lane = tid & 63;
    int w = tid >> 6;
    int wm = w >> 1, wn = w & 1;

    f32x4 acc[4][4];
    #pragma unroll
    for (int mi = 0; mi < 4; mi++)
        #pragma unroll
        for (int nj = 0; nj < 4; nj++)
            #pragma unroll
            for (int r = 0; r < 4; r++) acc[mi][nj][r] = 0.f;

    int srow = lane >> 2;                               // row within 16
    int sseg = ((lane & 3) ^ ((srow >> 1) & 3)) * 16;   // logical source seg
    int c = lane & 15;
    int kqp = (((lane >> 4) ^ ((c >> 1) & 3))) * 16;    // swizzled phys chunk

    for (int d0 = 0; d0 < 1024; d0 += 64) {
        __syncthreads();
        #pragma unroll
        for (int j = 0; j < 2; j++) {
            int r = w * 32 + j * 16 + srow;
            gld16(Ag + (size_t)(m0 + r) * 1024 + d0 + sseg, As + (w * 32 + j * 16) * 64);
            gld16(Bg + (size_t)(n0 + r) * 1024 + d0 + sseg, Bs + (w * 32 + j * 16) * 64);
        }
        __syncthreads();
        fp16x8 a[4], b[4];
        #pragma unroll
        for (int mi = 0; mi < 4; mi++)
            a[mi] = *(const fp16x8*)(As + (wm * 64 + mi * 16 + c) * 64 + kqp);
        #pragma unroll
        for (int nj = 0; nj < 4; nj++)
            b[nj] = *(const fp16x8*)(Bs + (wn * 64 + nj * 16 + c) * 64 + kqp);
        #pragma unroll
        for (int mi = 0; mi < 4; mi++)
            #pragma unroll
            for (int nj = 0; nj < 4; nj++)
                acc[mi][nj] = __builtin_amdgcn_mfma_f32_16x16x32_f16(a[mi], b[nj], acc[mi][nj], 0, 0, 0);
    }

    // ---- epilogue ----
    int gmb = m0 + wm * 64;
    int kk = gmb / 192, sb = gmb - kk * 192;
    int gnb = n0 + wn * 64;
    int qq = gnb / 192, tb = gnb - qq * 192;
    int rq = (lane >> 4) * 4;

    float rowm[4][4];
    float colm[4];
    #pragma unroll
    for (int mi = 0; mi < 4; mi++)
        #pragma unroll
        for (int r = 0; r < 4; r++) rowm[mi][r] = -3.4e38f;
    #pragma unroll
    for (int nj = 0; nj < 4; nj++) colm[nj] = -3.4e38f;

    #pragma unroll
    for (int mi = 0; mi < 4; mi++) {
        #pragma unroll
        for (int r = 0; r < 4; r++) {
            int s = sb + mi * 16 + rq + r;
            const float* srow_p = sg + (size_t)s * 192 + tb;
            #pragma unroll
            for (int nj = 0; nj < 4; nj++) {
                float m = srow_p[nj * 16 + c];
                float v = acc[mi][nj][r] * m;
                rowm[mi][r] = fmaxf(rowm[mi][r], v);
                colm[nj] = fmaxf(colm[nj], v);
            }
        }
    }
    #pragma unroll
    for (int nj = 0; nj < 4; nj++) {
        colm[nj] = fmaxf(colm[nj], __shfl_xor(colm[nj], 16));
        colm[nj] = fmaxf(colm[nj], __shfl_xor(colm[nj], 32));
    }
    if (lane < 16) {
        #pragma unroll
        for (int nj = 0; nj < 4; nj++)
            tmaxL[wm * 2 + wn][nj * 16 + lane] = fkey(colm[nj]);
    }
    #pragma unroll
    for (int st = 1; st <= 8; st <<= 1)
        #pragma unroll
        for (int mi = 0; mi < 4; mi++)
            #pragma unroll
            for (int r = 0; r < 4; r++)
                rowm[mi][r] = fmaxf(rowm[mi][r], __shfl_xor(rowm[mi][r], st));
    if (c == 0) {
        #pragma unroll
        for (int mi = 0; mi < 4; mi++)
            #pragma unroll
            for (int r = 0; r < 4; r++)
                smaxL[wm * 2 + wn][mi * 16 + rq + r] = fkey(rowm[mi][r]);
    }
    __syncthreads();

    #pragma unroll
    for (int rep = 0; rep < 2; rep++) {
        int idx = tid + rep * 256;
        int wp = idx >> 7;
        int which = (idx >> 6) & 1;
        int off = idx & 63;
        int wmf = wp >> 1, wnf = wp & 1;
        int kf = (m0 + wmf * 64) / 192, sbf = (m0 + wmf * 64) % 192;
        int qf = (n0 + wnf * 64) / 192, tbf = (n0 + wnf * 64) % 192;
        int jp = qf * 16 + kf;
        if (which == 0)
            atomicMax(&xkey[((size_t)l * 512 + 2 * jp) * 192 + tbf + off], tmaxL[wp][off]);
        else
            atomicMax(&xkey[((size_t)l * 512 + 2 * jp + 1) * 192 + sbf + off], smaxL[wp][off]);
    }
}

// ---------------- K3a: bn1 partial stats ----------------
__global__ __launch_bounds__(256) void k_bn1s(const unsigned* __restrict__ xkey,
                                              float* __restrict__ bn1acc) {
    int l = blockIdx.x / 48;
    int b = blockIdx.x - l * 48;
    const unsigned* xk = xkey + (size_t)l * 98304 + b * 2048;
    int tid = threadIdx.x;
    uint4 v1 = *(const uint4*)(xk + tid * 8);
    uint4 v2 = *(const uint4*)(xk + tid * 8 + 4);
    float s = 0.f, s2 = 0.f;
    float e;
    e = funkey(v1.x); s += e; s2 += e * e;
    e = funkey(v1.y); s += e; s2 += e * e;
    e = funkey(v1.z); s += e; s2 += e * e;
    e = funkey(v1.w); s += e; s2 += e * e;
    e = funkey(v2.x); s += e; s2 += e * e;
    e = funkey(v2.y); s += e; s2 += e * e;
    e = funkey(v2.z); s += e; s2 += e * e;
    e = funkey(v2.w); s += e; s2 += e * e;
    #pragma unroll
    for (int o = 32; o; o >>= 1) { s += __shfl_down(s, o); s2 += __shfl_down(s2, o); }
    if ((tid & 63) == 0) {
        atomicAdd(&bn1acc[l * 2], s);
        atomicAdd(&bn1acc[l * 2 + 1], s2);
    }
}

// ---------------- K3b: bn1 normalize -> fp16 x ----------------
__global__ __launch_bounds__(256) void k_bn1n(const unsigned* __restrict__ xkey,
                                              const float* __restrict__ bn1acc,
                                              const float* __restrict__ g1,
                                              const float* __restrict__ b1,
                                              _Float16* __restrict__ xh) {
    int idx = blockIdx.x * 256 + threadIdx.x;   // x4 elements
    int l = idx / 24576;
    float mu = bn1acc[l * 2] * (1.f / 98304.f);
    float var = bn1acc[l * 2 + 1] * (1.f / 98304.f) - mu * mu;
    float a1 = g1[l] * rsqrtf(var + EPS_);
    float c1 = b1[l] - mu * a1;
    uint4 kv = *(const uint4*)(xkey + (size_t)idx * 4);
    _Float16 h[4];
    h[0] = (_Float16)(funkey(kv.x) * a1 + c1);
    h[1] = (_Float16)(funkey(kv.y) * a1 + c1);
    h[2] = (_Float16)(funkey(kv.z) * a1 + c1);
    h[3] = (_Float16)(funkey(kv.w) * a1 + c1);
    *(uint2*)(xh + (size_t)idx * 4) = *(uint2*)h;
}

// ---------------- K4: fc2 fp16 GEMM + fused bn2 partial stats ----------------
__global__ __launch_bounds__(256) void k_fc2(const _Float16* __restrict__ xh,
                                             const _Float16* __restrict__ w2h,
                                             const float* __restrict__ b2,
                                             _Float16* __restrict__ hb,
                                             float* __restrict__ bn2sum,
                                             float* __restrict__ bn2sq) {
    int bid = blockIdx.x;
    int l = bid >> 6;
    int rem = bid & 63;
    int mt = rem & 3, nt = rem >> 2;
    int m0 = mt * 128, n0 = nt * 128;
    const char* Ag = (const char*)(xh + (size_t)l * 98304);
    const char* Bg = (const char*)(w2h + (size_t)l * 393216);

    __shared__ __align__(16) char As[8192];
    __shared__ __align__(16) char Bs[8192];

    int tid = threadIdx.x;
    int lane = tid & 63;
    int w = tid >> 6;
    int wm = w >> 1, wn = w & 1;

    f32x4 acc[4][4];
    #pragma unroll
    for (int mi = 0; mi < 4; mi++)
        #pragma unroll
        for (int nj = 0; nj < 4; nj++)
            #pragma unroll
            for (int r = 0; r < 4; r++) acc[mi][nj][r] = 0.f;

    int srow = lane >> 2;
    int sseg = ((lane & 3) ^ ((srow >> 1) & 3)) * 16;
    int c = lane & 15;
    int kqp = (((lane >> 4) ^ ((c >> 1) & 3))) * 16;

    for (int d0 = 0; d0 < 384; d0 += 64) {
        __syncthreads();
        #pragma unroll
        for (int j = 0; j < 2; j++) {
            int r = w * 32 + j * 16 + srow;
            gld16(Ag + (size_t)(m0 + r) * 384 + d0 + sseg, As + (w * 32 + j * 16) * 64);
            gld16(Bg + (size_t)(n0 + r) * 384 + d0 + sseg, Bs + (w * 32 + j * 16) * 64);
        }
        __syncthreads();
        fp16x8 a[4], b[4];
        #pragma unroll
        for (int mi = 0; mi < 4; mi++)
            a[mi] = *(const fp16x8*)(As + (wm * 64 + mi * 16 + c) * 64 + kqp);
        #pragma unroll
        for (int nj = 0; nj < 4; nj++)
            b[nj] = *(const fp16x8*)(Bs + (wn * 64 + nj * 16 + c) * 64 + kqp);
        #pragma unroll
        for (int mi = 0; mi < 4; mi++)
            #pragma unroll
            for (int nj = 0; nj < 4; nj++)
                acc[mi][nj] = __builtin_amdgcn_mfma_f32_16x16x32_f16(a[mi], b[nj], acc[mi][nj], 0, 0, 0);
    }

    int rq = (lane >> 4) * 4;
    _Float16* ho = hb + (size_t)l * 1048576;
    float colsum[4], colsq[4];
    #pragma unroll
    for (int nj = 0; nj < 4; nj++) { colsum[nj] = 0.f; colsq[nj] = 0.f; }
    #pragma unroll
    for (int nj = 0; nj < 4; nj++) {
        int gf = n0 + wn * 64 + nj * 16 + c;
        float bias = b2[l * 2048 + gf];
        #pragma unroll
        for (int mi = 0; mi < 4; mi++) {
            #pragma unroll
            for (int r = 0; r < 4; r++) {
                int gm = m0 + wm * 64 + mi * 16 + rq + r;
                float v = acc[mi][nj][r] + bias;
                ho[(size_t)gm * 2048 + gf] = (_Float16)v;
                colsum[nj] += v;
                colsq[nj] += v * v;
            }
        }
    }
    #pragma unroll
    for (int nj = 0; nj < 4; nj++) {
        colsum[nj] += __shfl_xor(colsum[nj], 16);
        colsum[nj] += __shfl_xor(colsum[nj], 32);
        colsq[nj]  += __shfl_xor(colsq[nj], 16);
        colsq[nj]  += __shfl_xor(colsq[nj], 32);
    }
    if (lane < 16) {
        #pragma unroll
        for (int nj = 0; nj < 4; nj++) {
            int gf = n0 + wn * 64 + nj * 16 + lane;
            atomicAdd(&bn2sum[l * 2048 + gf], colsum[nj]);
            atomicAdd(&bn2sq[l * 2048 + gf], colsq[nj]);
        }
    }
}

// ---------------- K6: bn2(inline stats) + relu + fc3 dot ----------------
__global__ __launch_bounds__(256) void k_fc3(const _Float16* __restrict__ hb,
                                             const float* __restrict__ bn2sum,
                                             const float* __restrict__ bn2sq,
                                             const float* __restrict__ g2,
                                             const float* __restrict__ bb2,
                                             const float* __restrict__ w3,
                                             const float* __restrict__ b3,
                                             float* __restrict__ ybuf) {
    int n = blockIdx.x & 511;
    int l = blockIdx.x >> 9;
    const _Float16* h = hb + ((size_t)l * 512 + n) * 2048;
    int tid = threadIdx.x;
    int f0 = tid * 8;
    fp16x8 hv = *(const fp16x8*)(h + f0);
    float sum = 0.f;
    #pragma unroll
    for (int j = 0; j < 8; j++) {
        int f = f0 + j;
        float mu = bn2sum[l * 2048 + f] * (1.f / 512.f);
        float var = bn2sq[l * 2048 + f] * (1.f / 512.f) - mu * mu;
        float a2 = g2[l * 2048 + f] * rsqrtf(var + EPS_);
        float c2 = bb2[l * 2048 + f] - mu * a2;
        float v = (float)hv[j] * a2 + c2;
        v = fmaxf(v, 0.f);
        sum += v * w3[l * 2048 + f];
    }
    __shared__ float red[4];
    int lane = tid & 63, w = tid >> 6;
    #pragma unroll
    for (int o = 32; o; o >>= 1) sum += __shfl_down(sum, o);
    if (lane == 0) red[w] = sum;
    __syncthreads();
    if (tid == 0) ybuf[l * 512 + n] = red[0] + red[1] + red[2] + red[3] + b3[l];
}

// ---------------- K7: pair-sum + bn3 + layer-sum + pair_labels ----------------
__global__ __launch_bounds__(256) void k_final(const float* __restrict__ ybuf,
                                               const float* __restrict__ g3,
                                               const float* __restrict__ bb3,
                                               const int* __restrict__ targets,
                                               float* __restrict__ out) {
    int tid = threadIdx.x;
    __shared__ float red[8];
    float scoreacc = 0.f;
    for (int l = 0; l < 8; l++) {
        float z = ybuf[l * 512 + 2 * tid] + ybuf[l * 512 + 2 * tid + 1];
        float s = z, s2 = z * z;
        int lane = tid & 63, w = tid >> 6;
        #pragma unroll
        for (int o = 32; o; o >>= 1) { s += __shfl_down(s, o); s2 += __shfl_down(s2, o); }
        if (lane == 0) { red[w] = s; red[4 + w] = s2; }
        __syncthreads();
        float S1 = red[0] + red[1] + red[2] + red[3];
        float S2 = red[4] + red[5] + red[6] + red[7];
        float mu = S1 * (1.f / 256.f);
        float var = S2 * (1.f / 256.f) - mu * mu;
        float rstd = rsqrtf(var + EPS_);
        scoreacc += g3[l] * (z - mu) * rstd + bb3[l];
        __syncthreads();
    }
    out[tid] = scoreacc;
    int i = tid >> 4, j = tid & 15;
    out[256 + tid] = (targets[i] == targets[j]) ? 1.f : 0.f;
}

extern "C" void kernel_launch(void* const* d_in, const int* in_sizes, int n_in,
                              void* d_out, int out_size, void* d_ws, size_t ws_size,
                              hipStream_t stream) {
    const float* q_feat = (const float*)d_in[0];
    const float* g_feat = (const float*)d_in[1];
    const int*   targets = (const int*)d_in[2];
    const float* se     = (const float*)d_in[3];
    const float* fc0_w  = (const float*)d_in[4];
    const float* fc0_b  = (const float*)d_in[5];
    const float* bn1_g  = (const float*)d_in[6];
    const float* bn1_b  = (const float*)d_in[7];
    const float* fc2_w  = (const float*)d_in[8];
    const float* fc2_b  = (const float*)d_in[9];
    const float* bn2_g  = (const float*)d_in[10];
    const float* bn2_b  = (const float*)d_in[11];
    const float* fc3_w  = (const float*)d_in[12];
    const float* fc3_b  = (const float*)d_in[13];
    const float* bn3_g  = (const float*)d_in[14];
    const float* bn3_b  = (const float*)d_in[15];

    float* ws = (float*)d_ws;
    _Float16* Qh   = (_Float16*)ws;
    float*    sig  = ws + 12582912;
    unsigned* xkey = (unsigned*)(ws + 12877824);
    _Float16* xh   = (_Float16*)(ws + 13664256);
    _Float16* w2h  = (_Float16*)(ws + 14057472);
    _Float16* hb   = (_Float16*)(ws + 15630336);
    float* bn2sum = ws + 19824640;
    float* bn2sq  = ws + 19841024;
    float* bn1acc = ws + 19857408;
    float* ybuf   = ws + 19857424;
    float* out  = (float*)d_out;

    hipMemsetAsync(xkey, 0, 786432 * sizeof(unsigned), stream);
    hipMemsetAsync(bn2sum, 0, (2 * 16384 + 16) * sizeof(float), stream);
    k_sig<<<288, 256, 0, stream>>>(se, sig);
    k_cvt<<<3072, 256, 0, stream>>>(fc2_w, w2h);
    k_fc0<<<1536, 256, 0, stream>>>(q_feat, g_feat, fc0_w, fc0_b, Qh);
    k_score<<<4608, 256, 0, stream>>>(Qh, sig, xkey);
    k_bn1s<<<384, 256, 0, stream>>>(xkey, bn1acc);
    k_bn1n<<<768, 256, 0, stream>>>(xkey, bn1acc, bn1_g, bn1_b, xh);
    k_fc2<<<512, 256, 0, stream>>>(xh, w2h, fc2_b, hb, bn2sum, bn2sq);
    k_fc3<<<4096, 256, 0, stream>>>(hb, bn2sum, bn2sq, bn2_g, bn2_b, fc3_w, fc3_b, ybuf);
    k_final<<<1, 256, 0, stream>>>(ybuf, bn3_g, bn3_b, targets, out);
}